// Round 12
// baseline (356.911 us; speedup 1.0000x reference)
//
#include <hip/hip_runtime.h>

typedef __bf16 bf16x8 __attribute__((ext_vector_type(8)));
typedef float f32x4 __attribute__((ext_vector_type(4)));
typedef unsigned short u16x8 __attribute__((ext_vector_type(8)));

__device__ __forceinline__ unsigned short f2bf(float f) {
  return __builtin_bit_cast(unsigned short, (__bf16)f);   // v_cvt_pk_bf16_f32, RNE
}

__device__ __forceinline__ void gload16(const void* g, void* l) {
  __builtin_amdgcn_global_load_lds((const __attribute__((address_space(1))) unsigned int*)g,
                                   (__attribute__((address_space(3))) unsigned int*)l,
                                   16, 0, 0);
}

// DPP row_ror reductions over 16-lane rows (VALU pipe, no LDS traffic)
template <int N>
__device__ __forceinline__ float rormax(float x) {
  int r = __builtin_amdgcn_update_dpp(0, __builtin_bit_cast(int, x), 0x120 + N, 0xF, 0xF, true);
  return fmaxf(x, __builtin_bit_cast(float, r));
}
template <int N>
__device__ __forceinline__ float rorsum(float x) {
  int r = __builtin_amdgcn_update_dpp(0, __builtin_bit_cast(int, x), 0x120 + N, 0xF, 0xF, true);
  return x + __builtin_bit_cast(float, r);
}
__device__ __forceinline__ float red16max(float x) {
  x = rormax<8>(x); x = rormax<4>(x); x = rormax<2>(x); return rormax<1>(x);
}
__device__ __forceinline__ float red16sum(float x) {
  x = rorsum<8>(x); x = rorsum<4>(x); x = rorsum<2>(x); return rorsum<1>(x);
}

// ---------------------------------------------------------------------------
// f32 -> bf16 conversion for {x, qkv_w, proj_w}
// ---------------------------------------------------------------------------
__global__ __launch_bounds__(256)
void cvt3_f32_bf16(const float* __restrict__ s0, unsigned short* __restrict__ d0, int n0,
                   const float* __restrict__ s1, unsigned short* __restrict__ d1, int n1,
                   const float* __restrict__ s2, unsigned short* __restrict__ d2)
{
  int blk = blockIdx.x;
  const float* s; unsigned short* d;
  if (blk < n0)            { s = s0; d = d0; }
  else if (blk < n0 + n1)  { s = s1; d = d1; blk -= n0; }
  else                     { s = s2; d = d2; blk -= n0 + n1; }
  const size_t e = ((size_t)blk * 256 + threadIdx.x) * 8;
  const float4 a = *(const float4*)(s + e);
  const float4 b = *(const float4*)(s + e + 4);
  u16x8 v;
  v[0] = f2bf(a.x); v[1] = f2bf(a.y); v[2] = f2bf(a.z); v[3] = f2bf(a.w);
  v[4] = f2bf(b.x); v[5] = f2bf(b.y); v[6] = f2bf(b.z); v[7] = f2bf(b.w);
  *(u16x8*)(d + e) = v;
}

// ---------------------------------------------------------------------------
// 256x256 8-phase GEMM (R8 config restored — best wall evidence).
// ---------------------------------------------------------------------------
#define STG(XS, Xg, buf, half, kt)                                              \
  { gload16((Xg) + (size_t)((half)*128 + srow8) * K + (kt)*64 + scol,           \
            (XS) + (buf)*32768 + (half)*16384 + wid*1024);                      \
    gload16((Xg) + (size_t)((half)*128 + 64 + srow8) * K + (kt)*64 + scol,      \
            (XS) + (buf)*32768 + (half)*16384 + 8192 + wid*1024); }

#define LDA(buf, ih)                                                            \
  { _Pragma("unroll") for (int i = 0; i < 4; ++i) {                             \
      const int ro = (buf)*32768 + arow + ((ih)*64 + i*16)*128;                 \
      af[i][0] = *(const bf16x8*)(As + ro + cbs0);                              \
      af[i][1] = *(const bf16x8*)(As + ro + cbs1); } }

#define LDB(buf, jh, BF)                                                        \
  { _Pragma("unroll") for (int j = 0; j < 2; ++j) {                             \
      const int ro = (buf)*32768 + brow + (((jh)*2 + j)*16)*128;                \
      BF[j][0] = *(const bf16x8*)(Bs + ro + cbs0);                              \
      BF[j][1] = *(const bf16x8*)(Bs + ro + cbs1); } }

#define MM(ih, jh, BF)                                                          \
  { _Pragma("unroll") for (int i = 0; i < 4; ++i)                               \
    _Pragma("unroll") for (int j = 0; j < 2; ++j)                               \
    _Pragma("unroll") for (int kk = 0; kk < 2; ++kk)                            \
      acc[(ih)*4+i][(jh)*2+j] = __builtin_amdgcn_mfma_f32_16x16x32_bf16(        \
          af[i][kk], BF[j][kk], acc[(ih)*4+i][(jh)*2+j], 0, 0, 0); }

#define BAR1_12() { asm volatile("s_waitcnt lgkmcnt(8)" ::: "memory");          \
                    __builtin_amdgcn_s_barrier();                               \
                    asm volatile("s_waitcnt lgkmcnt(0)" ::: "memory");          \
                    __builtin_amdgcn_sched_barrier(0);                          \
                    __builtin_amdgcn_s_setprio(1); }
#define BAR1()    { __builtin_amdgcn_s_barrier();                               \
                    asm volatile("s_waitcnt lgkmcnt(0)" ::: "memory");          \
                    __builtin_amdgcn_sched_barrier(0);                          \
                    __builtin_amdgcn_s_setprio(1); }
#define BAR2()    { __builtin_amdgcn_s_setprio(0); __builtin_amdgcn_s_barrier(); }
#define BAR2V()   { __builtin_amdgcn_s_setprio(0);                              \
                    asm volatile("s_waitcnt vmcnt(4)" ::: "memory");            \
                    __builtin_amdgcn_s_barrier(); }

template <bool OUTBF16>
__global__ __launch_bounds__(512, 1)
void gemm256_bt(const unsigned short* __restrict__ Ap, const unsigned short* __restrict__ Bp,
                void* __restrict__ Outp, int M, int N, int K)
{
  extern __shared__ __align__(16) char smem[];
  char* const As = smem;            // [2][256 rows][64 k] bf16, 64KB
  char* const Bs = smem + 65536;
  const int tid = threadIdx.x;
  const int wid = tid >> 6, lane = tid & 63;
  const int wm = wid >> 2, wn = wid & 3;
  const int lg = lane >> 4, lr = lane & 15;

  const int gx = gridDim.x;
  const int nwg = gx * (int)gridDim.y;
  int bid = (int)blockIdx.y * gx + (int)blockIdx.x;
  bid = (bid & 7) * (nwg >> 3) + (bid >> 3);   // bijective: nwg % 8 == 0
  const int m0 = (bid / gx) * 256, n0 = (bid % gx) * 256;

  const int srow8 = wid * 8 + (lane >> 3);
  const int scol  = (((lane & 7) ^ (lane >> 3)) << 3);
  const unsigned short* const Ag = Ap + (size_t)m0 * K;
  const unsigned short* const Bg = Bp + (size_t)n0 * K;

  const int cbs0 = (lg * 16) ^ ((lr & 7) << 4);
  const int cbs1 = (64 + lg * 16) ^ ((lr & 7) << 4);
  const int arow = (wm * 128 + lr) * 128;
  const int brow = (wn * 64 + lr) * 128;

  const f32x4 z4 = {0.f, 0.f, 0.f, 0.f};
  f32x4 acc[8][4];
#pragma unroll
  for (int i = 0; i < 8; ++i)
#pragma unroll
    for (int j = 0; j < 4; ++j) acc[i][j] = z4;

  const int NKT = K >> 6;
  bf16x8 af[4][2], bf01[2][2], bf23[2][2];

  STG(As, Ag, 0, 0, 0); STG(As, Ag, 0, 1, 0);
  STG(Bs, Bg, 0, 0, 0); STG(Bs, Bg, 0, 1, 0);
  STG(Bs, Bg, 1, 0, 1); STG(Bs, Bg, 1, 1, 1);
  asm volatile("s_waitcnt vmcnt(4)" ::: "memory");
  __builtin_amdgcn_s_barrier();

  for (int it = 0; it < (NKT >> 1); ++it) {
    const int t1  = 2 * it + 1;
    const int t0n = (2 * it + 2 < NKT) ? 2 * it + 2 : NKT - 1;
    const int t1n = (t1 + 2 < NKT) ? t1 + 2 : NKT - 1;

    LDA(0, 0); LDB(0, 0, bf01); STG(As, Ag, 1, 0, t1);
    BAR1_12(); MM(0, 0, bf01); BAR2();
    LDB(0, 1, bf23); STG(As, Ag, 1, 1, t1);
    BAR1(); MM(0, 1, bf23); BAR2();
    LDA(0, 1); STG(Bs, Bg, 0, 0, t0n);
    BAR1(); MM(1, 0, bf01); BAR2();
    STG(Bs, Bg, 0, 1, t0n);
    BAR1(); MM(1, 1, bf23); BAR2V();
    LDA(1, 0); LDB(1, 0, bf01); STG(As, Ag, 0, 0, t0n);
    BAR1_12(); MM(0, 0, bf01); BAR2();
    LDB(1, 1, bf23); STG(As, Ag, 0, 1, t0n);
    BAR1(); MM(0, 1, bf23); BAR2();
    LDA(1, 1); STG(Bs, Bg, 1, 0, t1n);
    BAR1(); MM(1, 0, bf01); BAR2();
    STG(Bs, Bg, 1, 1, t1n);
    BAR1(); MM(1, 1, bf23); BAR2V();
  }
  asm volatile("s_waitcnt vmcnt(0)" ::: "memory");

#pragma unroll
  for (int i = 0; i < 8; ++i)
#pragma unroll
    for (int j = 0; j < 4; ++j)
#pragma unroll
      for (int r = 0; r < 4; ++r) {
        const int row = m0 + wm * 128 + i * 16 + lg * 4 + r;
        const int col = n0 + wn * 64 + j * 16 + lr;
        const float val = acc[i][j][r];
        if (OUTBF16) ((unsigned short*)Outp)[(size_t)row * N + col] = f2bf(val);
        else         ((float*)Outp)[(size_t)row * N + col] = val;
      }
}

// ---------------------------------------------------------------------------
// GEMM (m97 structure) + XCD swizzle — gemm3 (N=2048: 512 blocks).
// ---------------------------------------------------------------------------
template <bool OUTBF16>
__global__ __launch_bounds__(256, 2)
void gemm_bt16(const unsigned short* __restrict__ Ap, const unsigned short* __restrict__ Bp,
               void* __restrict__ Outp, int M, int N, int K)
{
  __shared__ __align__(16) char smA[128 * 128];
  __shared__ __align__(16) char smB[128 * 128];
  const int tid = threadIdx.x;
  const int wid = tid >> 6, lane = tid & 63;
  const int wr = wid >> 1, wc = wid & 1;
  const int lg = lane >> 4, lr = lane & 15;

  const int gx = gridDim.x;
  const int nwg = gx * gridDim.y;
  int bid = blockIdx.y * gx + blockIdx.x;
  bid = (bid & 7) * (nwg >> 3) + (bid >> 3);
  const int m0 = (bid / gx) * 128, n0 = (bid % gx) * 128;

  const int srow = wid * 8 + (lane >> 3);
  const int scol = (((lane & 7) ^ (lane >> 3)) << 3);
  const int lbase = wid * 1024;

  const f32x4 z4 = {0.f, 0.f, 0.f, 0.f};
  f32x4 acc[4][4];
#pragma unroll
  for (int i = 0; i < 4; ++i)
#pragma unroll
    for (int j = 0; j < 4; ++j) acc[i][j] = z4;

  for (int k0 = 0; k0 < K; k0 += 64) {
    __syncthreads();
#pragma unroll
    for (int c = 0; c < 4; ++c) {
      const int row = c * 32 + srow;
      gload16(Ap + (size_t)(m0 + row) * K + k0 + scol, smA + c * 4096 + lbase);
      gload16(Bp + (size_t)(n0 + row) * K + k0 + scol, smB + c * 4096 + lbase);
    }
    __syncthreads();
#pragma unroll
    for (int kk = 0; kk < 2; ++kk) {
      const int cb = (kk * 32 + lg * 8) * 2;
      bf16x8 a4[4], b4[4];
#pragma unroll
      for (int i = 0; i < 4; ++i) {
        const int row = wr * 64 + i * 16 + lr;
        a4[i] = *(const bf16x8*)(smA + row * 128 + (cb ^ ((row & 7) << 4)));
      }
#pragma unroll
      for (int j = 0; j < 4; ++j) {
        const int row = wc * 64 + j * 16 + lr;
        b4[j] = *(const bf16x8*)(smB + row * 128 + (cb ^ ((row & 7) << 4)));
      }
#pragma unroll
      for (int i = 0; i < 4; ++i)
#pragma unroll
        for (int j = 0; j < 4; ++j)
          acc[i][j] = __builtin_amdgcn_mfma_f32_16x16x32_bf16(a4[i], b4[j], acc[i][j], 0, 0, 0);
    }
  }
#pragma unroll
  for (int i = 0; i < 4; ++i)
#pragma unroll
    for (int j = 0; j < 4; ++j)
#pragma unroll
      for (int r = 0; r < 4; ++r) {
        const int row = m0 + wr * 64 + i * 16 + lg * 4 + r;
        const int col = n0 + wc * 64 + j * 16 + lr;
        const float val = acc[i][j][r];
        if (OUTBF16) ((unsigned short*)Outp)[(size_t)row * N + col] = f2bf(val);
        else         ((float*)Outp)[(size_t)row * N + col] = val;
      }
}

// ---------------------------------------------------------------------------
// V transpose: qkv V-part -> vT[(bh*128+d)*2048 + t]   (unchanged)
// ---------------------------------------------------------------------------
__global__ __launch_bounds__(256)
void vtrans(const unsigned short* __restrict__ qkv, unsigned short* __restrict__ vT)
{
  constexpr int T = 2048, ROWS = 6144;
  const int bh = blockIdx.y, b = bh >> 4, h = bh & 15;
  const int t0 = blockIdx.x * 64;
  const int tid = threadIdx.x;
  __shared__ __align__(16) char Sc[64 * 256];

#pragma unroll
  for (int c = 0; c < 4; ++c) {
    const int row = c * 16 + (tid >> 4);
    const int col = (tid & 15) * 8;
    u16x8 v = *(const u16x8*)(qkv + (size_t)(b * T + t0 + row) * ROWS + 4096 + h * 128 + col);
    *(u16x8*)(Sc + row * 256 + ((col * 2) ^ ((row & 7) << 4))) = v;
  }
  __syncthreads();
#pragma unroll
  for (int c = 0; c < 4; ++c) {
    const int d = c * 32 + (tid >> 3);
    const int t = (tid & 7) * 8;
    u16x8 v;
#pragma unroll
    for (int i = 0; i < 8; ++i)
      v[i] = *(const unsigned short*)(Sc + (t + i) * 256 + ((d * 2) ^ (((t + i) & 7) << 4)));
    *(u16x8*)(vT + ((size_t)bh * 128 + d) * 2048 + t0 + t) = v;
  }
}

// ---------------------------------------------------------------------------
// Flash attention v9: QBLK=128 via rb=2 row-blocks per wave (each kf/vf LDS
// read feeds 2 MFMA -> halves LDS bytes per q-row); P overlays the K buffer
// (K dead after QK; extra barrier C makes it safe); LDS 64KB -> 2 blocks/CU.
// Grid 512, paired-qt mapping (CU's two blocks sum to 17 K-tiles).
// ---------------------------------------------------------------------------
__global__ __launch_bounds__(256, 2)
void attn_fwd(const unsigned short* __restrict__ qkv, const unsigned short* __restrict__ vT,
              unsigned short* __restrict__ outp)
{
  constexpr int T = 2048, ROWS = 6144;
  const int blk = blockIdx.x;
  const int g = blk >> 5;                       // 0..15
  const int qt = (g < 8) ? 15 - g : g - 8;      // pair sums const per CU
  const int bh = blk & 31;
  const int b = bh >> 4, h = bh & 15;
  const int q0 = qt * 128;
  const int tid = threadIdx.x;
  const int wid = tid >> 6, lane = tid & 63;
  const int lg = lane >> 4, lr = lane & 15;

  __shared__ __align__(16) char Ks[128 * 256];  // 32KB [128 k][128 d]; P after QK
  __shared__ __align__(16) char Vt[128 * 256];  // 32KB [128 d][128 k] swizzled

  const int srow = wid * 4 + (lane >> 4);
  const int scol = (((lane & 15) ^ (srow & 7)) << 3);

  // Q fragments for both row-blocks
  bf16x8 qf[2][4];
#pragma unroll
  for (int rb = 0; rb < 2; ++rb) {
    const size_t qrow = (size_t)(b * T + q0 + rb * 64 + wid * 16 + lr) * ROWS + h * 128;
#pragma unroll
    for (int kd = 0; kd < 4; ++kd)
      qf[rb][kd] = __builtin_bit_cast(bf16x8, *(const u16x8*)(qkv + qrow + kd * 32 + lg * 8));
  }

  const f32x4 z4 = {0.f, 0.f, 0.f, 0.f};
  f32x4 oacc[2][8];
#pragma unroll
  for (int rb = 0; rb < 2; ++rb)
#pragma unroll
    for (int jj = 0; jj < 8; ++jj) oacc[rb][jj] = z4;
  float mrow[2][4], lsum[2][4];
#pragma unroll
  for (int rb = 0; rb < 2; ++rb)
#pragma unroll
    for (int r = 0; r < 4; ++r) { mrow[rb][r] = -1e30f; lsum[rb][r] = 0.f; }
  const float scale2 = 0.12751745f;   // (1/sqrt(128)) * log2(e)

  const int nt = qt + 1;
  for (int kt = 0; kt < nt; ++kt) {
    __syncthreads();   // A: prev tile's PV reads (Ks-as-P, Vt) done
#pragma unroll
    for (int c = 0; c < 8; ++c) {
      gload16(qkv + (size_t)(b * T + kt * 128 + c * 16 + srow) * ROWS + 2048 + h * 128 + scol,
              Ks + c * 4096 + wid * 1024);
      gload16(vT + ((size_t)bh * 128 + c * 16 + srow) * 2048 + kt * 128 + scol,
              Vt + c * 4096 + wid * 1024);
    }
    asm volatile("s_waitcnt vmcnt(0)" ::: "memory");
    __syncthreads();   // B: tiles resident

    // S = Q K^T for both row-blocks (kf read once, 2 MFMA)
    f32x4 sf[2][8];
#pragma unroll
    for (int rb = 0; rb < 2; ++rb)
#pragma unroll
      for (int j = 0; j < 8; ++j) sf[rb][j] = z4;
#pragma unroll
    for (int kd = 0; kd < 4; ++kd) {
      const int cb = (kd * 32 + lg * 8) * 2;
#pragma unroll
      for (int j = 0; j < 8; ++j) {
        const int row = j * 16 + lr;
        bf16x8 kf = *(const bf16x8*)(Ks + row * 256 + (cb ^ ((row & 7) << 4)));
        sf[0][j] = __builtin_amdgcn_mfma_f32_16x16x32_bf16(qf[0][kd], kf, sf[0][j], 0, 0, 0);
        sf[1][j] = __builtin_amdgcn_mfma_f32_16x16x32_bf16(qf[1][kd], kf, sf[1][j], 0, 0, 0);
      }
    }

    // softmax in log2 domain, per row-block
    const bool diag = (kt == nt - 1);
    float pm[2][4];
#pragma unroll
    for (int rb = 0; rb < 2; ++rb) {
#pragma unroll
      for (int j = 0; j < 8; ++j)
#pragma unroll
        for (int r = 0; r < 4; ++r) {
          float s = sf[rb][j][r] * scale2;
          const int key = kt * 128 + j * 16 + lr;
          const int qi  = q0 + rb * 64 + wid * 16 + lg * 4 + r;
          if (diag && key > qi) s = -1e30f;
          sf[rb][j][r] = s;
        }
#pragma unroll
      for (int r = 0; r < 4; ++r) {
        float a0 = fmaxf(fmaxf(sf[rb][0][r], sf[rb][1][r]), fmaxf(sf[rb][2][r], sf[rb][3][r]));
        float a1 = fmaxf(fmaxf(sf[rb][4][r], sf[rb][5][r]), fmaxf(sf[rb][6][r], sf[rb][7][r]));
        pm[rb][r] = red16max(fmaxf(a0, a1));
      }
    }
    float growth = -1e30f;
#pragma unroll
    for (int rb = 0; rb < 2; ++rb)
#pragma unroll
      for (int r = 0; r < 4; ++r) growth = fmaxf(growth, pm[rb][r] - mrow[rb][r]);
    const bool resc = !__all(growth <= 11.5f);
    float alpha[2][4];
    if (resc) {
#pragma unroll
      for (int rb = 0; rb < 2; ++rb)
#pragma unroll
        for (int r = 0; r < 4; ++r) {
          const float mn = fmaxf(mrow[rb][r], pm[rb][r]);
          alpha[rb][r] = exp2f(mrow[rb][r] - mn);
          mrow[rb][r] = mn;
        }
    }
    float rs[2][4] = {{0.f, 0.f, 0.f, 0.f}, {0.f, 0.f, 0.f, 0.f}};
#pragma unroll
    for (int rb = 0; rb < 2; ++rb)
#pragma unroll
      for (int j = 0; j < 8; ++j)
#pragma unroll
        for (int r = 0; r < 4; ++r) {
          const float p = exp2f(sf[rb][j][r] - mrow[rb][r]);
          sf[rb][j][r] = p;
          rs[rb][r] += p;
        }
#pragma unroll
    for (int rb = 0; rb < 2; ++rb) {
      if (resc) {
#pragma unroll
        for (int r = 0; r < 4; ++r) lsum[rb][r] = lsum[rb][r] * alpha[rb][r] + red16sum(rs[rb][r]);
      } else {
#pragma unroll
        for (int r = 0; r < 4; ++r) lsum[rb][r] += red16sum(rs[rb][r]);
      }
    }

    __syncthreads();   // C: all waves done reading Ks -> safe to overwrite with P

    // P -> Ks buffer as Ps[128 q][128 k] (wave-private rows)
#pragma unroll
    for (int rb = 0; rb < 2; ++rb)
#pragma unroll
      for (int j = 0; j < 8; ++j)
#pragma unroll
        for (int r = 0; r < 4; ++r) {
          const int prow = rb * 64 + wid * 16 + lg * 4 + r;
          const int pcol = j * 16 + lr;
          *(unsigned short*)(Ks + prow * 256 + ((pcol * 2) ^ ((prow & 7) << 4))) = f2bf(sf[rb][j][r]);
        }
    if (resc) {
#pragma unroll
      for (int rb = 0; rb < 2; ++rb)
#pragma unroll
        for (int jj = 0; jj < 8; ++jj)
#pragma unroll
          for (int r = 0; r < 4; ++r) oacc[rb][jj][r] *= alpha[rb][r];
    }
    asm volatile("s_waitcnt lgkmcnt(0)" ::: "memory");
    __builtin_amdgcn_sched_barrier(0);

    // O += P V  (vf read once, 2 MFMA)
#pragma unroll
    for (int kk = 0; kk < 4; ++kk) {
      const int pcb = (kk * 32 + lg * 8) * 2;
      const int prow0 = wid * 16 + lr;
      const int prow1 = 64 + wid * 16 + lr;
      bf16x8 pf0 = *(const bf16x8*)(Ks + prow0 * 256 + (pcb ^ ((prow0 & 7) << 4)));
      bf16x8 pf1 = *(const bf16x8*)(Ks + prow1 * 256 + (pcb ^ ((prow1 & 7) << 4)));
#pragma unroll
      for (int jj = 0; jj < 8; ++jj) {
        const int vrow = jj * 16 + lr;
        bf16x8 vf = *(const bf16x8*)(Vt + vrow * 256 + (pcb ^ ((vrow & 7) << 4)));
        oacc[0][jj] = __builtin_amdgcn_mfma_f32_16x16x32_bf16(pf0, vf, oacc[0][jj], 0, 0, 0);
        oacc[1][jj] = __builtin_amdgcn_mfma_f32_16x16x32_bf16(pf1, vf, oacc[1][jj], 0, 0, 0);
      }
    }
  }

  // epilogue
#pragma unroll
  for (int rb = 0; rb < 2; ++rb)
#pragma unroll
    for (int jj = 0; jj < 8; ++jj)
#pragma unroll
      for (int r = 0; r < 4; ++r) {
        const int q = q0 + rb * 64 + wid * 16 + lg * 4 + r;
        const int col = h * 128 + jj * 16 + lr;
        const float o = oacc[rb][jj][r] / lsum[rb][r];
        outp[(size_t)(b * T + q) * 2048 + col] = f2bf(o);
      }
}

// ---------------------------------------------------------------------------
extern "C" void kernel_launch(void* const* d_in, const int* in_sizes, int n_in,
                              void* d_out, int out_size, void* d_ws, size_t ws_size,
                              hipStream_t stream) {
  (void)in_sizes; (void)n_in; (void)out_size; (void)ws_size;
  const float* x     = (const float*)d_in[0];   // [2,2048,2048]
  const float* qkvw  = (const float*)d_in[1];   // [6144,2048]
  const float* projw = (const float*)d_in[2];   // [2048,2048]

  unsigned short* qkvb   = (unsigned short*)d_ws;               // [4096][6144]
  unsigned short* attnb  = qkvb   + (size_t)4096 * 6144;        // [4096][2048]
  unsigned short* xb     = attnb  + (size_t)4096 * 2048;        // [4096][2048]
  unsigned short* qkvwb  = xb     + (size_t)4096 * 2048;        // [6144][2048]
  unsigned short* projwb = qkvwb  + (size_t)6144 * 2048;        // [2048][2048]
  unsigned short* vT     = xb;                                  // overlay (xb dead after gemm1)
  float* out = (float*)d_out;                                   // [4096][2048] f32

  static bool attr_set = false;
  if (!attr_set) {
    hipFuncSetAttribute((const void*)gemm256_bt<true>,
                        hipFuncAttributeMaxDynamicSharedMemorySize, 131072);
    attr_set = true;
  }

  cvt3_f32_bf16<<<4096 + 6144 + 2048, 256, 0, stream>>>(
      x, xb, 4096, qkvw, qkvwb, 6144, projw, projwb);
  gemm256_bt<true><<<dim3(6144 / 256, 4096 / 256), 512, 131072, stream>>>(
      xb, qkvwb, qkvb, 4096, 6144, 2048);
  vtrans<<<dim3(32, 32), 256, 0, stream>>>(qkvb, vT);
  attn_fwd<<<512, 256, 0, stream>>>(qkvb, vT, attnb);
  gemm_bt16<false><<<dim3(2048 / 128, 4096 / 128), 256, 0, stream>>>(
      attnb, projwb, out, 4096, 2048, 2048);
}

// Round 13
// 268.029 us; speedup vs baseline: 1.3316x; 1.3316x over previous
//
#include <hip/hip_runtime.h>

typedef __bf16 bf16x8 __attribute__((ext_vector_type(8)));
typedef float f32x4 __attribute__((ext_vector_type(4)));
typedef unsigned short u16x8 __attribute__((ext_vector_type(8)));

__device__ __forceinline__ unsigned short f2bf(float f) {
  return __builtin_bit_cast(unsigned short, (__bf16)f);   // v_cvt_pk_bf16_f32, RNE
}

__device__ __forceinline__ void gload16(const void* g, void* l) {
  __builtin_amdgcn_global_load_lds((const __attribute__((address_space(1))) unsigned int*)g,
                                   (__attribute__((address_space(3))) unsigned int*)l,
                                   16, 0, 0);
}

// DPP row_ror reductions over 16-lane rows (VALU pipe, no LDS traffic)
template <int N>
__device__ __forceinline__ float rormax(float x) {
  int r = __builtin_amdgcn_update_dpp(0, __builtin_bit_cast(int, x), 0x120 + N, 0xF, 0xF, true);
  return fmaxf(x, __builtin_bit_cast(float, r));
}
template <int N>
__device__ __forceinline__ float rorsum(float x) {
  int r = __builtin_amdgcn_update_dpp(0, __builtin_bit_cast(int, x), 0x120 + N, 0xF, 0xF, true);
  return x + __builtin_bit_cast(float, r);
}
__device__ __forceinline__ float red16max(float x) {
  x = rormax<8>(x); x = rormax<4>(x); x = rormax<2>(x); return rormax<1>(x);
}
__device__ __forceinline__ float red16sum(float x) {
  x = rorsum<8>(x); x = rorsum<4>(x); x = rorsum<2>(x); return rorsum<1>(x);
}

// ---------------------------------------------------------------------------
// f32 -> bf16 conversion for {x, qkv_w, proj_w}
// ---------------------------------------------------------------------------
__global__ __launch_bounds__(256)
void cvt3_f32_bf16(const float* __restrict__ s0, unsigned short* __restrict__ d0, int n0,
                   const float* __restrict__ s1, unsigned short* __restrict__ d1, int n1,
                   const float* __restrict__ s2, unsigned short* __restrict__ d2)
{
  int blk = blockIdx.x;
  const float* s; unsigned short* d;
  if (blk < n0)            { s = s0; d = d0; }
  else if (blk < n0 + n1)  { s = s1; d = d1; blk -= n0; }
  else                     { s = s2; d = d2; blk -= n0 + n1; }
  const size_t e = ((size_t)blk * 256 + threadIdx.x) * 8;
  const float4 a = *(const float4*)(s + e);
  const float4 b = *(const float4*)(s + e + 4);
  u16x8 v;
  v[0] = f2bf(a.x); v[1] = f2bf(a.y); v[2] = f2bf(a.z); v[3] = f2bf(a.w);
  v[4] = f2bf(b.x); v[5] = f2bf(b.y); v[6] = f2bf(b.z); v[7] = f2bf(b.w);
  *(u16x8*)(d + e) = v;
}

// ---------------------------------------------------------------------------
// 256x256 8-phase GEMM (R8 config — best wall evidence).
// ---------------------------------------------------------------------------
#define STG(XS, Xg, buf, half, kt)                                              \
  { gload16((Xg) + (size_t)((half)*128 + srow8) * K + (kt)*64 + scol,           \
            (XS) + (buf)*32768 + (half)*16384 + wid*1024);                      \
    gload16((Xg) + (size_t)((half)*128 + 64 + srow8) * K + (kt)*64 + scol,      \
            (XS) + (buf)*32768 + (half)*16384 + 8192 + wid*1024); }

#define LDA(buf, ih)                                                            \
  { _Pragma("unroll") for (int i = 0; i < 4; ++i) {                             \
      const int ro = (buf)*32768 + arow + ((ih)*64 + i*16)*128;                 \
      af[i][0] = *(const bf16x8*)(As + ro + cbs0);                              \
      af[i][1] = *(const bf16x8*)(As + ro + cbs1); } }

#define LDB(buf, jh, BF)                                                        \
  { _Pragma("unroll") for (int j = 0; j < 2; ++j) {                             \
      const int ro = (buf)*32768 + brow + (((jh)*2 + j)*16)*128;                \
      BF[j][0] = *(const bf16x8*)(Bs + ro + cbs0);                              \
      BF[j][1] = *(const bf16x8*)(Bs + ro + cbs1); } }

#define MM(ih, jh, BF)                                                          \
  { _Pragma("unroll") for (int i = 0; i < 4; ++i)                               \
    _Pragma("unroll") for (int j = 0; j < 2; ++j)                               \
    _Pragma("unroll") for (int kk = 0; kk < 2; ++kk)                            \
      acc[(ih)*4+i][(jh)*2+j] = __builtin_amdgcn_mfma_f32_16x16x32_bf16(        \
          af[i][kk], BF[j][kk], acc[(ih)*4+i][(jh)*2+j], 0, 0, 0); }

#define BAR1_12() { asm volatile("s_waitcnt lgkmcnt(8)" ::: "memory");          \
                    __builtin_amdgcn_s_barrier();                               \
                    asm volatile("s_waitcnt lgkmcnt(0)" ::: "memory");          \
                    __builtin_amdgcn_sched_barrier(0);                          \
                    __builtin_amdgcn_s_setprio(1); }
#define BAR1()    { __builtin_amdgcn_s_barrier();                               \
                    asm volatile("s_waitcnt lgkmcnt(0)" ::: "memory");          \
                    __builtin_amdgcn_sched_barrier(0);                          \
                    __builtin_amdgcn_s_setprio(1); }
#define BAR2()    { __builtin_amdgcn_s_setprio(0); __builtin_amdgcn_s_barrier(); }
#define BAR2V()   { __builtin_amdgcn_s_setprio(0);                              \
                    asm volatile("s_waitcnt vmcnt(4)" ::: "memory");            \
                    __builtin_amdgcn_s_barrier(); }

template <bool OUTBF16>
__global__ __launch_bounds__(512, 1)
void gemm256_bt(const unsigned short* __restrict__ Ap, const unsigned short* __restrict__ Bp,
                void* __restrict__ Outp, int M, int N, int K)
{
  extern __shared__ __align__(16) char smem[];
  char* const As = smem;            // [2][256 rows][64 k] bf16, 64KB
  char* const Bs = smem + 65536;
  const int tid = threadIdx.x;
  const int wid = tid >> 6, lane = tid & 63;
  const int wm = wid >> 2, wn = wid & 3;
  const int lg = lane >> 4, lr = lane & 15;

  const int gx = gridDim.x;
  const int nwg = gx * (int)gridDim.y;
  int bid = (int)blockIdx.y * gx + (int)blockIdx.x;
  bid = (bid & 7) * (nwg >> 3) + (bid >> 3);   // bijective: nwg % 8 == 0
  const int m0 = (bid / gx) * 256, n0 = (bid % gx) * 256;

  const int srow8 = wid * 8 + (lane >> 3);
  const int scol  = (((lane & 7) ^ (lane >> 3)) << 3);
  const unsigned short* const Ag = Ap + (size_t)m0 * K;
  const unsigned short* const Bg = Bp + (size_t)n0 * K;

  const int cbs0 = (lg * 16) ^ ((lr & 7) << 4);
  const int cbs1 = (64 + lg * 16) ^ ((lr & 7) << 4);
  const int arow = (wm * 128 + lr) * 128;
  const int brow = (wn * 64 + lr) * 128;

  const f32x4 z4 = {0.f, 0.f, 0.f, 0.f};
  f32x4 acc[8][4];
#pragma unroll
  for (int i = 0; i < 8; ++i)
#pragma unroll
    for (int j = 0; j < 4; ++j) acc[i][j] = z4;

  const int NKT = K >> 6;
  bf16x8 af[4][2], bf01[2][2], bf23[2][2];

  STG(As, Ag, 0, 0, 0); STG(As, Ag, 0, 1, 0);
  STG(Bs, Bg, 0, 0, 0); STG(Bs, Bg, 0, 1, 0);
  STG(Bs, Bg, 1, 0, 1); STG(Bs, Bg, 1, 1, 1);
  asm volatile("s_waitcnt vmcnt(4)" ::: "memory");
  __builtin_amdgcn_s_barrier();

  for (int it = 0; it < (NKT >> 1); ++it) {
    const int t1  = 2 * it + 1;
    const int t0n = (2 * it + 2 < NKT) ? 2 * it + 2 : NKT - 1;
    const int t1n = (t1 + 2 < NKT) ? t1 + 2 : NKT - 1;

    LDA(0, 0); LDB(0, 0, bf01); STG(As, Ag, 1, 0, t1);
    BAR1_12(); MM(0, 0, bf01); BAR2();
    LDB(0, 1, bf23); STG(As, Ag, 1, 1, t1);
    BAR1(); MM(0, 1, bf23); BAR2();
    LDA(0, 1); STG(Bs, Bg, 0, 0, t0n);
    BAR1(); MM(1, 0, bf01); BAR2();
    STG(Bs, Bg, 0, 1, t0n);
    BAR1(); MM(1, 1, bf23); BAR2V();
    LDA(1, 0); LDB(1, 0, bf01); STG(As, Ag, 0, 0, t0n);
    BAR1_12(); MM(0, 0, bf01); BAR2();
    LDB(1, 1, bf23); STG(As, Ag, 0, 1, t0n);
    BAR1(); MM(0, 1, bf23); BAR2();
    LDA(1, 1); STG(Bs, Bg, 1, 0, t1n);
    BAR1(); MM(1, 0, bf01); BAR2();
    STG(Bs, Bg, 1, 1, t1n);
    BAR1(); MM(1, 1, bf23); BAR2V();
  }
  asm volatile("s_waitcnt vmcnt(0)" ::: "memory");

#pragma unroll
  for (int i = 0; i < 8; ++i)
#pragma unroll
    for (int j = 0; j < 4; ++j)
#pragma unroll
      for (int r = 0; r < 4; ++r) {
        const int row = m0 + wm * 128 + i * 16 + lg * 4 + r;
        const int col = n0 + wn * 64 + j * 16 + lr;
        const float val = acc[i][j][r];
        if (OUTBF16) ((unsigned short*)Outp)[(size_t)row * N + col] = f2bf(val);
        else         ((float*)Outp)[(size_t)row * N + col] = val;
      }
}

// ---------------------------------------------------------------------------
// GEMM (m97 structure) + XCD swizzle — gemm3 (N=2048: 512 blocks).
// ---------------------------------------------------------------------------
template <bool OUTBF16>
__global__ __launch_bounds__(256, 2)
void gemm_bt16(const unsigned short* __restrict__ Ap, const unsigned short* __restrict__ Bp,
               void* __restrict__ Outp, int M, int N, int K)
{
  __shared__ __align__(16) char smA[128 * 128];
  __shared__ __align__(16) char smB[128 * 128];
  const int tid = threadIdx.x;
  const int wid = tid >> 6, lane = tid & 63;
  const int wr = wid >> 1, wc = wid & 1;
  const int lg = lane >> 4, lr = lane & 15;

  const int gx = gridDim.x;
  const int nwg = gx * gridDim.y;
  int bid = blockIdx.y * gx + blockIdx.x;
  bid = (bid & 7) * (nwg >> 3) + (bid >> 3);
  const int m0 = (bid / gx) * 128, n0 = (bid % gx) * 128;

  const int srow = wid * 8 + (lane >> 3);
  const int scol = (((lane & 7) ^ (lane >> 3)) << 3);
  const int lbase = wid * 1024;

  const f32x4 z4 = {0.f, 0.f, 0.f, 0.f};
  f32x4 acc[4][4];
#pragma unroll
  for (int i = 0; i < 4; ++i)
#pragma unroll
    for (int j = 0; j < 4; ++j) acc[i][j] = z4;

  for (int k0 = 0; k0 < K; k0 += 64) {
    __syncthreads();
#pragma unroll
    for (int c = 0; c < 4; ++c) {
      const int row = c * 32 + srow;
      gload16(Ap + (size_t)(m0 + row) * K + k0 + scol, smA + c * 4096 + lbase);
      gload16(Bp + (size_t)(n0 + row) * K + k0 + scol, smB + c * 4096 + lbase);
    }
    __syncthreads();
#pragma unroll
    for (int kk = 0; kk < 2; ++kk) {
      const int cb = (kk * 32 + lg * 8) * 2;
      bf16x8 a4[4], b4[4];
#pragma unroll
      for (int i = 0; i < 4; ++i) {
        const int row = wr * 64 + i * 16 + lr;
        a4[i] = *(const bf16x8*)(smA + row * 128 + (cb ^ ((row & 7) << 4)));
      }
#pragma unroll
      for (int j = 0; j < 4; ++j) {
        const int row = wc * 64 + j * 16 + lr;
        b4[j] = *(const bf16x8*)(smB + row * 128 + (cb ^ ((row & 7) << 4)));
      }
#pragma unroll
      for (int i = 0; i < 4; ++i)
#pragma unroll
        for (int j = 0; j < 4; ++j)
          acc[i][j] = __builtin_amdgcn_mfma_f32_16x16x32_bf16(a4[i], b4[j], acc[i][j], 0, 0, 0);
    }
  }
#pragma unroll
  for (int i = 0; i < 4; ++i)
#pragma unroll
    for (int j = 0; j < 4; ++j)
#pragma unroll
      for (int r = 0; r < 4; ++r) {
        const int row = m0 + wr * 64 + i * 16 + lg * 4 + r;
        const int col = n0 + wc * 64 + j * 16 + lr;
        const float val = acc[i][j][r];
        if (OUTBF16) ((unsigned short*)Outp)[(size_t)row * N + col] = f2bf(val);
        else         ((float*)Outp)[(size_t)row * N + col] = val;
      }
}

// ---------------------------------------------------------------------------
// V transpose: qkv V-part -> vT[(bh*128+d)*2048 + t]   (unchanged)
// ---------------------------------------------------------------------------
__global__ __launch_bounds__(256)
void vtrans(const unsigned short* __restrict__ qkv, unsigned short* __restrict__ vT)
{
  constexpr int T = 2048, ROWS = 6144;
  const int bh = blockIdx.y, b = bh >> 4, h = bh & 15;
  const int t0 = blockIdx.x * 64;
  const int tid = threadIdx.x;
  __shared__ __align__(16) char Sc[64 * 256];

#pragma unroll
  for (int c = 0; c < 4; ++c) {
    const int row = c * 16 + (tid >> 4);
    const int col = (tid & 15) * 8;
    u16x8 v = *(const u16x8*)(qkv + (size_t)(b * T + t0 + row) * ROWS + 4096 + h * 128 + col);
    *(u16x8*)(Sc + row * 256 + ((col * 2) ^ ((row & 7) << 4))) = v;
  }
  __syncthreads();
#pragma unroll
  for (int c = 0; c < 4; ++c) {
    const int d = c * 32 + (tid >> 3);
    const int t = (tid & 7) * 8;
    u16x8 v;
#pragma unroll
    for (int i = 0; i < 8; ++i)
      v[i] = *(const unsigned short*)(Sc + (t + i) * 256 + ((d * 2) ^ (((t + i) & 7) << 4)));
    *(u16x8*)(vT + ((size_t)bh * 128 + d) * 2048 + t0 + t) = v;
  }
}

// ---------------------------------------------------------------------------
// Flash attention v10 = R8's v8 + split-staged K/V with counted vmcnt:
// K(kt+1) issued after QK's readers-done barrier (hides under softmax+PV),
// V(kt+1) after PV's readers-done barrier (hides under next QK+softmax);
// residency waits are vmcnt(8) (8-oldest = exactly the needed tile).
// Raw s_barrier (no __syncthreads vmcnt(0) drain). Tail: clamped re-stage
// keeps wait counts uniform. LDS 80KB, 2 blocks/CU, qt descending.
// ---------------------------------------------------------------------------
__global__ __launch_bounds__(256, 2)
void attn_fwd(const unsigned short* __restrict__ qkv, const unsigned short* __restrict__ vT,
              unsigned short* __restrict__ outp)
{
  constexpr int T = 2048, ROWS = 6144;
  const int blk = blockIdx.x;
  const int qt = 31 - (blk >> 5);       // heavy tiles first
  const int bh = blk & 31;
  const int b = bh >> 4, h = bh & 15;
  const int q0 = qt * 64;
  const int tid = threadIdx.x;
  const int wid = tid >> 6, lane = tid & 63;
  const int lg = lane >> 4, lr = lane & 15;

  __shared__ __align__(16) char Ks[128 * 256];  // 32KB [128 k][128 d] swizzled
  __shared__ __align__(16) char Vt[128 * 256];  // 32KB [128 d][128 k] swizzled
  __shared__ __align__(16) char Ps[64 * 256];   // 16KB [64 q][128 k] swizzled

  const int srow = wid * 4 + (lane >> 4);
  const int scol = (((lane & 15) ^ (srow & 7)) << 3);

  const size_t qrow = (size_t)(b * T + q0 + wid * 16 + lr) * ROWS + h * 128;
  bf16x8 qf[4];
#pragma unroll
  for (int kd = 0; kd < 4; ++kd)
    qf[kd] = __builtin_bit_cast(bf16x8, *(const u16x8*)(qkv + qrow + kd * 32 + lg * 8));

  const f32x4 z4 = {0.f, 0.f, 0.f, 0.f};
  f32x4 oacc[8];
#pragma unroll
  for (int jj = 0; jj < 8; ++jj) oacc[jj] = z4;
  float mrow[4] = {-1e30f, -1e30f, -1e30f, -1e30f};
  float lsum[4] = {0.f, 0.f, 0.f, 0.f};
  const float scale2 = 0.12751745f;   // (1/sqrt(128)) * log2(e)

  const int nt = (qt >> 1) + 1;

  // prologue: stage K(0) then V(0)  (order matters for vmcnt counting)
#pragma unroll
  for (int c = 0; c < 8; ++c)
    gload16(qkv + (size_t)(b * T + c * 16 + srow) * ROWS + 2048 + h * 128 + scol,
            Ks + c * 4096 + wid * 1024);
#pragma unroll
  for (int c = 0; c < 8; ++c)
    gload16(vT + ((size_t)bh * 128 + c * 16 + srow) * 2048 + scol,
            Vt + c * 4096 + wid * 1024);

  for (int kt = 0; kt < nt; ++kt) {
    const int ktn = (kt + 1 < nt) ? kt + 1 : nt - 1;   // clamped tail re-stage

    // B1: my K(kt) slice landed (V(kt) + anything newer still in flight)
    asm volatile("s_waitcnt vmcnt(8)" ::: "memory");
    __builtin_amdgcn_s_barrier();      // all waves' K slices landed
    __builtin_amdgcn_sched_barrier(0);

    // S = Q K^T
    f32x4 sf[8];
#pragma unroll
    for (int j = 0; j < 8; ++j) sf[j] = z4;
#pragma unroll
    for (int kd = 0; kd < 4; ++kd) {
      const int cb = (kd * 32 + lg * 8) * 2;
#pragma unroll
      for (int j = 0; j < 8; ++j) {
        const int row = j * 16 + lr;
        bf16x8 kf = *(const bf16x8*)(Ks + row * 256 + (cb ^ ((row & 7) << 4)));
        sf[j] = __builtin_amdgcn_mfma_f32_16x16x32_bf16(qf[kd], kf, sf[j], 0, 0, 0);
      }
    }
    asm volatile("s_waitcnt lgkmcnt(0)" ::: "memory");  // QK reads done (regs hold data)
    __builtin_amdgcn_s_barrier();      // B2: Ks readers done everywhere
    // stage K(kt+1) -> Ks (lands under softmax + PV)
#pragma unroll
    for (int c = 0; c < 8; ++c)
      gload16(qkv + (size_t)(b * T + ktn * 128 + c * 16 + srow) * ROWS + 2048 + h * 128 + scol,
              Ks + c * 4096 + wid * 1024);

    // softmax in log2 domain; mask only the last tile
    const bool diag = (kt == nt - 1);
#pragma unroll
    for (int j = 0; j < 8; ++j)
#pragma unroll
      for (int r = 0; r < 4; ++r) {
        float s = sf[j][r] * scale2;
        const int key = kt * 128 + j * 16 + lr;
        const int qi  = q0 + wid * 16 + lg * 4 + r;
        if (diag && key > qi) s = -1e30f;
        sf[j][r] = s;
      }
    float pm[4];
#pragma unroll
    for (int r = 0; r < 4; ++r) {
      float m0 = fmaxf(fmaxf(sf[0][r], sf[1][r]), fmaxf(sf[2][r], sf[3][r]));
      float m1 = fmaxf(fmaxf(sf[4][r], sf[5][r]), fmaxf(sf[6][r], sf[7][r]));
      pm[r] = red16max(fmaxf(m0, m1));
    }
    const float growth = fmaxf(fmaxf(pm[0] - mrow[0], pm[1] - mrow[1]),
                               fmaxf(pm[2] - mrow[2], pm[3] - mrow[3]));
    const bool resc = !__all(growth <= 11.5f);
    float alpha[4];
    if (resc) {
#pragma unroll
      for (int r = 0; r < 4; ++r) {
        const float mn = fmaxf(mrow[r], pm[r]);
        alpha[r] = exp2f(mrow[r] - mn);
        mrow[r] = mn;
      }
    }
    float rs[4] = {0.f, 0.f, 0.f, 0.f};
#pragma unroll
    for (int j = 0; j < 8; ++j)
#pragma unroll
      for (int r = 0; r < 4; ++r) {
        const float p = exp2f(sf[j][r] - mrow[r]);
        sf[j][r] = p;
        rs[r] += p;
      }
    if (resc) {
#pragma unroll
      for (int r = 0; r < 4; ++r) lsum[r] = lsum[r] * alpha[r] + red16sum(rs[r]);
    } else {
#pragma unroll
      for (int r = 0; r < 4; ++r) lsum[r] += red16sum(rs[r]);
    }

    // P -> Ps (wave-private rows)
#pragma unroll
    for (int j = 0; j < 8; ++j)
#pragma unroll
      for (int r = 0; r < 4; ++r) {
        const int prow = wid * 16 + lg * 4 + r;
        const int pcol = j * 16 + lr;
        *(unsigned short*)(Ps + prow * 256 + ((pcol * 2) ^ ((prow & 7) << 4))) = f2bf(sf[j][r]);
      }
    if (resc) {
#pragma unroll
      for (int jj = 0; jj < 8; ++jj)
#pragma unroll
        for (int r = 0; r < 4; ++r) oacc[jj][r] *= alpha[r];
    }

    // B3: my V(kt) slice landed (K(kt+1) in flight); then everyone's
    asm volatile("s_waitcnt vmcnt(8)" ::: "memory");
    __builtin_amdgcn_s_barrier();
    // same-wave DS ordering for Ps (rule #18)
    asm volatile("s_waitcnt lgkmcnt(0)" ::: "memory");
    __builtin_amdgcn_sched_barrier(0);

    // O += P V
#pragma unroll
    for (int kk = 0; kk < 4; ++kk) {
      const int prow = wid * 16 + lr;
      const int pcb = (kk * 32 + lg * 8) * 2;
      bf16x8 pf = *(const bf16x8*)(Ps + prow * 256 + (pcb ^ ((prow & 7) << 4)));
#pragma unroll
      for (int jj = 0; jj < 8; ++jj) {
        const int vrow = jj * 16 + lr;
        bf16x8 vf = *(const bf16x8*)(Vt + vrow * 256 + (pcb ^ ((vrow & 7) << 4)));
        oacc[jj] = __builtin_amdgcn_mfma_f32_16x16x32_bf16(pf, vf, oacc[jj], 0, 0, 0);
      }
    }
    asm volatile("s_waitcnt lgkmcnt(0)" ::: "memory");  // PV reads done
    __builtin_amdgcn_s_barrier();      // B4: Vt readers done everywhere
    // stage V(kt+1) -> Vt (lands under next QK + softmax)
#pragma unroll
    for (int c = 0; c < 8; ++c)
      gload16(vT + ((size_t)bh * 128 + c * 16 + srow) * 2048 + ktn * 128 + scol,
              Vt + c * 4096 + wid * 1024);
  }
  asm volatile("s_waitcnt vmcnt(0)" ::: "memory");  // drain trailing stages

  // epilogue
#pragma unroll
  for (int jj = 0; jj < 8; ++jj)
#pragma unroll
    for (int r = 0; r < 4; ++r) {
      const int q = q0 + wid * 16 + lg * 4 + r;
      const int col = h * 128 + jj * 16 + lr;
      const float o = oacc[jj][r] / lsum[r];
      outp[(size_t)(b * T + q) * 2048 + col] = f2bf(o);
    }
}

// ---------------------------------------------------------------------------
extern "C" void kernel_launch(void* const* d_in, const int* in_sizes, int n_in,
                              void* d_out, int out_size, void* d_ws, size_t ws_size,
                              hipStream_t stream) {
  (void)in_sizes; (void)n_in; (void)out_size; (void)ws_size;
  const float* x     = (const float*)d_in[0];   // [2,2048,2048]
  const float* qkvw  = (const float*)d_in[1];   // [6144,2048]
  const float* projw = (const float*)d_in[2];   // [2048,2048]

  unsigned short* qkvb   = (unsigned short*)d_ws;               // [4096][6144]
  unsigned short* attnb  = qkvb   + (size_t)4096 * 6144;        // [4096][2048]
  unsigned short* xb     = attnb  + (size_t)4096 * 2048;        // [4096][2048]
  unsigned short* qkvwb  = xb     + (size_t)4096 * 2048;        // [6144][2048]
  unsigned short* projwb = qkvwb  + (size_t)6144 * 2048;        // [2048][2048]
  unsigned short* vT     = xb;                                  // overlay (xb dead after gemm1)
  float* out = (float*)d_out;                                   // [4096][2048] f32

  static bool attr_set = false;
  if (!attr_set) {
    hipFuncSetAttribute((const void*)gemm256_bt<true>,
                        hipFuncAttributeMaxDynamicSharedMemorySize, 131072);
    attr_set = true;
  }

  cvt3_f32_bf16<<<4096 + 6144 + 2048, 256, 0, stream>>>(
      x, xb, 4096, qkvw, qkvwb, 6144, projw, projwb);
  gemm256_bt<true><<<dim3(6144 / 256, 4096 / 256), 512, 131072, stream>>>(
      xb, qkvwb, qkvb, 4096, 6144, 2048);
  vtrans<<<dim3(32, 32), 256, 0, stream>>>(qkvb, vT);
  attn_fwd<<<1024, 256, 0, stream>>>(qkvb, vT, attnb);
  gemm_bt16<false><<<dim3(2048 / 128, 4096 / 128), 256, 0, stream>>>(
      attnb, projwb, out, 4096, 2048, 2048);
}

// Round 14
// 264.265 us; speedup vs baseline: 1.3506x; 1.0142x over previous
//
#include <hip/hip_runtime.h>

typedef __bf16 bf16x8 __attribute__((ext_vector_type(8)));
typedef float f32x4 __attribute__((ext_vector_type(4)));
typedef unsigned short u16x8 __attribute__((ext_vector_type(8)));

__device__ __forceinline__ unsigned short f2bf(float f) {
  return __builtin_bit_cast(unsigned short, (__bf16)f);   // v_cvt_pk_bf16_f32, RNE
}

__device__ __forceinline__ void gload16(const void* g, void* l) {
  __builtin_amdgcn_global_load_lds((const __attribute__((address_space(1))) unsigned int*)g,
                                   (__attribute__((address_space(3))) unsigned int*)l,
                                   16, 0, 0);
}

// DPP row_ror reductions over 16-lane rows (VALU pipe, no LDS traffic)
template <int N>
__device__ __forceinline__ float rormax(float x) {
  int r = __builtin_amdgcn_update_dpp(0, __builtin_bit_cast(int, x), 0x120 + N, 0xF, 0xF, true);
  return fmaxf(x, __builtin_bit_cast(float, r));
}
template <int N>
__device__ __forceinline__ float rorsum(float x) {
  int r = __builtin_amdgcn_update_dpp(0, __builtin_bit_cast(int, x), 0x120 + N, 0xF, 0xF, true);
  return x + __builtin_bit_cast(float, r);
}
__device__ __forceinline__ float red16max(float x) {
  x = rormax<8>(x); x = rormax<4>(x); x = rormax<2>(x); return rormax<1>(x);
}
__device__ __forceinline__ float red16sum(float x) {
  x = rorsum<8>(x); x = rorsum<4>(x); x = rorsum<2>(x); return rorsum<1>(x);
}

// ---------------------------------------------------------------------------
// f32 -> bf16 conversion for {x, qkv_w, proj_w}
// ---------------------------------------------------------------------------
__global__ __launch_bounds__(256)
void cvt3_f32_bf16(const float* __restrict__ s0, unsigned short* __restrict__ d0, int n0,
                   const float* __restrict__ s1, unsigned short* __restrict__ d1, int n1,
                   const float* __restrict__ s2, unsigned short* __restrict__ d2)
{
  int blk = blockIdx.x;
  const float* s; unsigned short* d;
  if (blk < n0)            { s = s0; d = d0; }
  else if (blk < n0 + n1)  { s = s1; d = d1; blk -= n0; }
  else                     { s = s2; d = d2; blk -= n0 + n1; }
  const size_t e = ((size_t)blk * 256 + threadIdx.x) * 8;
  const float4 a = *(const float4*)(s + e);
  const float4 b = *(const float4*)(s + e + 4);
  u16x8 v;
  v[0] = f2bf(a.x); v[1] = f2bf(a.y); v[2] = f2bf(a.z); v[3] = f2bf(a.w);
  v[4] = f2bf(b.x); v[5] = f2bf(b.y); v[6] = f2bf(b.z); v[7] = f2bf(b.w);
  *(u16x8*)(d + e) = v;
}

// ---------------------------------------------------------------------------
// 256x256 8-phase GEMM (R8 config — best wall evidence). Unchanged.
// ---------------------------------------------------------------------------
#define STG(XS, Xg, buf, half, kt)                                              \
  { gload16((Xg) + (size_t)((half)*128 + srow8) * K + (kt)*64 + scol,           \
            (XS) + (buf)*32768 + (half)*16384 + wid*1024);                      \
    gload16((Xg) + (size_t)((half)*128 + 64 + srow8) * K + (kt)*64 + scol,      \
            (XS) + (buf)*32768 + (half)*16384 + 8192 + wid*1024); }

#define LDA(buf, ih)                                                            \
  { _Pragma("unroll") for (int i = 0; i < 4; ++i) {                             \
      const int ro = (buf)*32768 + arow + ((ih)*64 + i*16)*128;                 \
      af[i][0] = *(const bf16x8*)(As + ro + cbs0);                              \
      af[i][1] = *(const bf16x8*)(As + ro + cbs1); } }

#define LDB(buf, jh, BF)                                                        \
  { _Pragma("unroll") for (int j = 0; j < 2; ++j) {                             \
      const int ro = (buf)*32768 + brow + (((jh)*2 + j)*16)*128;                \
      BF[j][0] = *(const bf16x8*)(Bs + ro + cbs0);                              \
      BF[j][1] = *(const bf16x8*)(Bs + ro + cbs1); } }

#define MM(ih, jh, BF)                                                          \
  { _Pragma("unroll") for (int i = 0; i < 4; ++i)                               \
    _Pragma("unroll") for (int j = 0; j < 2; ++j)                               \
    _Pragma("unroll") for (int kk = 0; kk < 2; ++kk)                            \
      acc[(ih)*4+i][(jh)*2+j] = __builtin_amdgcn_mfma_f32_16x16x32_bf16(        \
          af[i][kk], BF[j][kk], acc[(ih)*4+i][(jh)*2+j], 0, 0, 0); }

#define BAR1_12() { asm volatile("s_waitcnt lgkmcnt(8)" ::: "memory");          \
                    __builtin_amdgcn_s_barrier();                               \
                    asm volatile("s_waitcnt lgkmcnt(0)" ::: "memory");          \
                    __builtin_amdgcn_sched_barrier(0);                          \
                    __builtin_amdgcn_s_setprio(1); }
#define BAR1()    { __builtin_amdgcn_s_barrier();                               \
                    asm volatile("s_waitcnt lgkmcnt(0)" ::: "memory");          \
                    __builtin_amdgcn_sched_barrier(0);                          \
                    __builtin_amdgcn_s_setprio(1); }
#define BAR2()    { __builtin_amdgcn_s_setprio(0); __builtin_amdgcn_s_barrier(); }
#define BAR2V()   { __builtin_amdgcn_s_setprio(0);                              \
                    asm volatile("s_waitcnt vmcnt(4)" ::: "memory");            \
                    __builtin_amdgcn_s_barrier(); }

template <bool OUTBF16>
__global__ __launch_bounds__(512, 1)
void gemm256_bt(const unsigned short* __restrict__ Ap, const unsigned short* __restrict__ Bp,
                void* __restrict__ Outp, int M, int N, int K)
{
  extern __shared__ __align__(16) char smem[];
  char* const As = smem;            // [2][256 rows][64 k] bf16, 64KB
  char* const Bs = smem + 65536;
  const int tid = threadIdx.x;
  const int wid = tid >> 6, lane = tid & 63;
  const int wm = wid >> 2, wn = wid & 3;
  const int lg = lane >> 4, lr = lane & 15;

  const int gx = gridDim.x;
  const int nwg = gx * (int)gridDim.y;
  int bid = (int)blockIdx.y * gx + (int)blockIdx.x;
  bid = (bid & 7) * (nwg >> 3) + (bid >> 3);   // bijective: nwg % 8 == 0
  const int m0 = (bid / gx) * 256, n0 = (bid % gx) * 256;

  const int srow8 = wid * 8 + (lane >> 3);
  const int scol  = (((lane & 7) ^ (lane >> 3)) << 3);
  const unsigned short* const Ag = Ap + (size_t)m0 * K;
  const unsigned short* const Bg = Bp + (size_t)n0 * K;

  const int cbs0 = (lg * 16) ^ ((lr & 7) << 4);
  const int cbs1 = (64 + lg * 16) ^ ((lr & 7) << 4);
  const int arow = (wm * 128 + lr) * 128;
  const int brow = (wn * 64 + lr) * 128;

  const f32x4 z4 = {0.f, 0.f, 0.f, 0.f};
  f32x4 acc[8][4];
#pragma unroll
  for (int i = 0; i < 8; ++i)
#pragma unroll
    for (int j = 0; j < 4; ++j) acc[i][j] = z4;

  const int NKT = K >> 6;
  bf16x8 af[4][2], bf01[2][2], bf23[2][2];

  STG(As, Ag, 0, 0, 0); STG(As, Ag, 0, 1, 0);
  STG(Bs, Bg, 0, 0, 0); STG(Bs, Bg, 0, 1, 0);
  STG(Bs, Bg, 1, 0, 1); STG(Bs, Bg, 1, 1, 1);
  asm volatile("s_waitcnt vmcnt(4)" ::: "memory");
  __builtin_amdgcn_s_barrier();

  for (int it = 0; it < (NKT >> 1); ++it) {
    const int t1  = 2 * it + 1;
    const int t0n = (2 * it + 2 < NKT) ? 2 * it + 2 : NKT - 1;
    const int t1n = (t1 + 2 < NKT) ? t1 + 2 : NKT - 1;

    LDA(0, 0); LDB(0, 0, bf01); STG(As, Ag, 1, 0, t1);
    BAR1_12(); MM(0, 0, bf01); BAR2();
    LDB(0, 1, bf23); STG(As, Ag, 1, 1, t1);
    BAR1(); MM(0, 1, bf23); BAR2();
    LDA(0, 1); STG(Bs, Bg, 0, 0, t0n);
    BAR1(); MM(1, 0, bf01); BAR2();
    STG(Bs, Bg, 0, 1, t0n);
    BAR1(); MM(1, 1, bf23); BAR2V();
    LDA(1, 0); LDB(1, 0, bf01); STG(As, Ag, 0, 0, t0n);
    BAR1_12(); MM(0, 0, bf01); BAR2();
    LDB(1, 1, bf23); STG(As, Ag, 0, 1, t0n);
    BAR1(); MM(0, 1, bf23); BAR2();
    LDA(1, 1); STG(Bs, Bg, 1, 0, t1n);
    BAR1(); MM(1, 0, bf01); BAR2();
    STG(Bs, Bg, 1, 1, t1n);
    BAR1(); MM(1, 1, bf23); BAR2V();
  }
  asm volatile("s_waitcnt vmcnt(0)" ::: "memory");

#pragma unroll
  for (int i = 0; i < 8; ++i)
#pragma unroll
    for (int j = 0; j < 4; ++j)
#pragma unroll
      for (int r = 0; r < 4; ++r) {
        const int row = m0 + wm * 128 + i * 16 + lg * 4 + r;
        const int col = n0 + wn * 64 + j * 16 + lr;
        const float val = acc[i][j][r];
        if (OUTBF16) ((unsigned short*)Outp)[(size_t)row * N + col] = f2bf(val);
        else         ((float*)Outp)[(size_t)row * N + col] = val;
      }
}

// ---------------------------------------------------------------------------
// GEMM (m97 structure) + XCD swizzle — gemm3 (N=2048: 512 blocks).
// ---------------------------------------------------------------------------
template <bool OUTBF16>
__global__ __launch_bounds__(256, 2)
void gemm_bt16(const unsigned short* __restrict__ Ap, const unsigned short* __restrict__ Bp,
               void* __restrict__ Outp, int M, int N, int K)
{
  __shared__ __align__(16) char smA[128 * 128];
  __shared__ __align__(16) char smB[128 * 128];
  const int tid = threadIdx.x;
  const int wid = tid >> 6, lane = tid & 63;
  const int wr = wid >> 1, wc = wid & 1;
  const int lg = lane >> 4, lr = lane & 15;

  const int gx = gridDim.x;
  const int nwg = gx * gridDim.y;
  int bid = blockIdx.y * gx + blockIdx.x;
  bid = (bid & 7) * (nwg >> 3) + (bid >> 3);
  const int m0 = (bid / gx) * 128, n0 = (bid % gx) * 128;

  const int srow = wid * 8 + (lane >> 3);
  const int scol = (((lane & 7) ^ (lane >> 3)) << 3);
  const int lbase = wid * 1024;

  const f32x4 z4 = {0.f, 0.f, 0.f, 0.f};
  f32x4 acc[4][4];
#pragma unroll
  for (int i = 0; i < 4; ++i)
#pragma unroll
    for (int j = 0; j < 4; ++j) acc[i][j] = z4;

  for (int k0 = 0; k0 < K; k0 += 64) {
    __syncthreads();
#pragma unroll
    for (int c = 0; c < 4; ++c) {
      const int row = c * 32 + srow;
      gload16(Ap + (size_t)(m0 + row) * K + k0 + scol, smA + c * 4096 + lbase);
      gload16(Bp + (size_t)(n0 + row) * K + k0 + scol, smB + c * 4096 + lbase);
    }
    __syncthreads();
#pragma unroll
    for (int kk = 0; kk < 2; ++kk) {
      const int cb = (kk * 32 + lg * 8) * 2;
      bf16x8 a4[4], b4[4];
#pragma unroll
      for (int i = 0; i < 4; ++i) {
        const int row = wr * 64 + i * 16 + lr;
        a4[i] = *(const bf16x8*)(smA + row * 128 + (cb ^ ((row & 7) << 4)));
      }
#pragma unroll
      for (int j = 0; j < 4; ++j) {
        const int row = wc * 64 + j * 16 + lr;
        b4[j] = *(const bf16x8*)(smB + row * 128 + (cb ^ ((row & 7) << 4)));
      }
#pragma unroll
      for (int i = 0; i < 4; ++i)
#pragma unroll
        for (int j = 0; j < 4; ++j)
          acc[i][j] = __builtin_amdgcn_mfma_f32_16x16x32_bf16(a4[i], b4[j], acc[i][j], 0, 0, 0);
    }
  }
#pragma unroll
  for (int i = 0; i < 4; ++i)
#pragma unroll
    for (int j = 0; j < 4; ++j)
#pragma unroll
      for (int r = 0; r < 4; ++r) {
        const int row = m0 + wr * 64 + i * 16 + lg * 4 + r;
        const int col = n0 + wc * 64 + j * 16 + lr;
        const float val = acc[i][j][r];
        if (OUTBF16) ((unsigned short*)Outp)[(size_t)row * N + col] = f2bf(val);
        else         ((float*)Outp)[(size_t)row * N + col] = val;
      }
}

// ---------------------------------------------------------------------------
// V transpose: qkv V-part -> vT[(bh*128+d)*2048 + t]   (unchanged)
// ---------------------------------------------------------------------------
__global__ __launch_bounds__(256)
void vtrans(const unsigned short* __restrict__ qkv, unsigned short* __restrict__ vT)
{
  constexpr int T = 2048, ROWS = 6144;
  const int bh = blockIdx.y, b = bh >> 4, h = bh & 15;
  const int t0 = blockIdx.x * 64;
  const int tid = threadIdx.x;
  __shared__ __align__(16) char Sc[64 * 256];

#pragma unroll
  for (int c = 0; c < 4; ++c) {
    const int row = c * 16 + (tid >> 4);
    const int col = (tid & 15) * 8;
    u16x8 v = *(const u16x8*)(qkv + (size_t)(b * T + t0 + row) * ROWS + 4096 + h * 128 + col);
    *(u16x8*)(Sc + row * 256 + ((col * 2) ^ ((row & 7) << 4))) = v;
  }
  __syncthreads();
#pragma unroll
  for (int c = 0; c < 4; ++c) {
    const int d = c * 32 + (tid >> 3);
    const int t = (tid & 7) * 8;
    u16x8 v;
#pragma unroll
    for (int i = 0; i < 8; ++i)
      v[i] = *(const unsigned short*)(Sc + (t + i) * 256 + ((d * 2) ^ (((t + i) & 7) << 4)));
    *(u16x8*)(vT + ((size_t)bh * 128 + d) * 2048 + t0 + t) = v;
  }
}

// ---------------------------------------------------------------------------
// Flash attention v8 + XCD-chunked head mapping: xcd = blk&7 hosts heads
// {4*xcd .. 4*xcd+3} (4MB K/V working set = one XCD L2). Per-CU qt spread
// identical to R8 (qt in {31-y,23-y,15-y,7-y}) -> any delta is locality.
// KVBLK=128, log2 softmax, T13 defer-max. LDS 80KB, 2 blocks/CU.
// ---------------------------------------------------------------------------
__global__ __launch_bounds__(256, 2)
void attn_fwd(const unsigned short* __restrict__ qkv, const unsigned short* __restrict__ vT,
              unsigned short* __restrict__ outp)
{
  constexpr int T = 2048, ROWS = 6144;
  const int blk = blockIdx.x;
  const int xcd = blk & 7, rr = blk >> 3;
  const int bh = xcd * 4 + (rr & 3);    // 4 heads per XCD -> L2-sized K/V set
  const int qt = 31 - (rr >> 2);        // heavy tiles first
  const int b = bh >> 4, h = bh & 15;
  const int q0 = qt * 64;
  const int tid = threadIdx.x;
  const int wid = tid >> 6, lane = tid & 63;
  const int lg = lane >> 4, lr = lane & 15;

  __shared__ __align__(16) char Ks[128 * 256];  // 32KB [128 k][128 d] swizzled
  __shared__ __align__(16) char Vt[128 * 256];  // 32KB [128 d][128 k] swizzled
  __shared__ __align__(16) char Ps[64 * 256];   // 16KB [64 q][128 k] swizzled

  const int srow = wid * 4 + (lane >> 4);
  const int scol = (((lane & 15) ^ (srow & 7)) << 3);

  const size_t qrow = (size_t)(b * T + q0 + wid * 16 + lr) * ROWS + h * 128;
  bf16x8 qf[4];
#pragma unroll
  for (int kd = 0; kd < 4; ++kd)
    qf[kd] = __builtin_bit_cast(bf16x8, *(const u16x8*)(qkv + qrow + kd * 32 + lg * 8));

  const f32x4 z4 = {0.f, 0.f, 0.f, 0.f};
  f32x4 oacc[8];
#pragma unroll
  for (int jj = 0; jj < 8; ++jj) oacc[jj] = z4;
  float mrow[4] = {-1e30f, -1e30f, -1e30f, -1e30f};
  float lsum[4] = {0.f, 0.f, 0.f, 0.f};
  const float scale2 = 0.12751745f;   // (1/sqrt(128)) * log2(e)

  const int nt = (qt >> 1) + 1;
  for (int kt = 0; kt < nt; ++kt) {
    __syncthreads();
#pragma unroll
    for (int c = 0; c < 8; ++c) {
      gload16(qkv + (size_t)(b * T + kt * 128 + c * 16 + srow) * ROWS + 2048 + h * 128 + scol,
              Ks + c * 4096 + wid * 1024);
      gload16(vT + ((size_t)bh * 128 + c * 16 + srow) * 2048 + kt * 128 + scol,
              Vt + c * 4096 + wid * 1024);
    }
    asm volatile("s_waitcnt vmcnt(0)" ::: "memory");
    __syncthreads();

    f32x4 sf[8];
#pragma unroll
    for (int j = 0; j < 8; ++j) sf[j] = z4;
#pragma unroll
    for (int kd = 0; kd < 4; ++kd) {
      const int cb = (kd * 32 + lg * 8) * 2;
#pragma unroll
      for (int j = 0; j < 8; ++j) {
        const int row = j * 16 + lr;
        bf16x8 kf = *(const bf16x8*)(Ks + row * 256 + (cb ^ ((row & 7) << 4)));
        sf[j] = __builtin_amdgcn_mfma_f32_16x16x32_bf16(qf[kd], kf, sf[j], 0, 0, 0);
      }
    }

    const bool diag = (kt == nt - 1);
#pragma unroll
    for (int j = 0; j < 8; ++j)
#pragma unroll
      for (int r = 0; r < 4; ++r) {
        float s = sf[j][r] * scale2;
        const int key = kt * 128 + j * 16 + lr;
        const int qi  = q0 + wid * 16 + lg * 4 + r;
        if (diag && key > qi) s = -1e30f;
        sf[j][r] = s;
      }
    float pm[4];
#pragma unroll
    for (int r = 0; r < 4; ++r) {
      float m0 = fmaxf(fmaxf(sf[0][r], sf[1][r]), fmaxf(sf[2][r], sf[3][r]));
      float m1 = fmaxf(fmaxf(sf[4][r], sf[5][r]), fmaxf(sf[6][r], sf[7][r]));
      pm[r] = red16max(fmaxf(m0, m1));
    }
    const float growth = fmaxf(fmaxf(pm[0] - mrow[0], pm[1] - mrow[1]),
                               fmaxf(pm[2] - mrow[2], pm[3] - mrow[3]));
    const bool resc = !__all(growth <= 11.5f);
    float alpha[4];
    if (resc) {
#pragma unroll
      for (int r = 0; r < 4; ++r) {
        const float mn = fmaxf(mrow[r], pm[r]);
        alpha[r] = exp2f(mrow[r] - mn);
        mrow[r] = mn;
      }
    }
    float rs[4] = {0.f, 0.f, 0.f, 0.f};
#pragma unroll
    for (int j = 0; j < 8; ++j)
#pragma unroll
      for (int r = 0; r < 4; ++r) {
        const float p = exp2f(sf[j][r] - mrow[r]);
        sf[j][r] = p;
        rs[r] += p;
      }
    if (resc) {
#pragma unroll
      for (int r = 0; r < 4; ++r) lsum[r] = lsum[r] * alpha[r] + red16sum(rs[r]);
    } else {
#pragma unroll
      for (int r = 0; r < 4; ++r) lsum[r] += red16sum(rs[r]);
    }

#pragma unroll
    for (int j = 0; j < 8; ++j)
#pragma unroll
      for (int r = 0; r < 4; ++r) {
        const int prow = wid * 16 + lg * 4 + r;
        const int pcol = j * 16 + lr;
        *(unsigned short*)(Ps + prow * 256 + ((pcol * 2) ^ ((prow & 7) << 4))) = f2bf(sf[j][r]);
      }
    if (resc) {
#pragma unroll
      for (int jj = 0; jj < 8; ++jj)
#pragma unroll
        for (int r = 0; r < 4; ++r) oacc[jj][r] *= alpha[r];
    }
    asm volatile("s_waitcnt lgkmcnt(0)" ::: "memory");
    __builtin_amdgcn_sched_barrier(0);

#pragma unroll
    for (int kk = 0; kk < 4; ++kk) {
      const int prow = wid * 16 + lr;
      const int pcb = (kk * 32 + lg * 8) * 2;
      bf16x8 pf = *(const bf16x8*)(Ps + prow * 256 + (pcb ^ ((prow & 7) << 4)));
#pragma unroll
      for (int jj = 0; jj < 8; ++jj) {
        const int vrow = jj * 16 + lr;
        bf16x8 vf = *(const bf16x8*)(Vt + vrow * 256 + (pcb ^ ((vrow & 7) << 4)));
        oacc[jj] = __builtin_amdgcn_mfma_f32_16x16x32_bf16(pf, vf, oacc[jj], 0, 0, 0);
      }
    }
  }

  // epilogue
#pragma unroll
  for (int jj = 0; jj < 8; ++jj)
#pragma unroll
    for (int r = 0; r < 4; ++r) {
      const int q = q0 + wid * 16 + lg * 4 + r;
      const int col = h * 128 + jj * 16 + lr;
      const float o = oacc[jj][r] / lsum[r];
      outp[(size_t)(b * T + q) * 2048 + col] = f2bf(o);
    }
}

// ---------------------------------------------------------------------------
extern "C" void kernel_launch(void* const* d_in, const int* in_sizes, int n_in,
                              void* d_out, int out_size, void* d_ws, size_t ws_size,
                              hipStream_t stream) {
  (void)in_sizes; (void)n_in; (void)out_size; (void)ws_size;
  const float* x     = (const float*)d_in[0];   // [2,2048,2048]
  const float* qkvw  = (const float*)d_in[1];   // [6144,2048]
  const float* projw = (const float*)d_in[2];   // [2048,2048]

  unsigned short* qkvb   = (unsigned short*)d_ws;               // [4096][6144]
  unsigned short* attnb  = qkvb   + (size_t)4096 * 6144;        // [4096][2048]
  unsigned short* xb     = attnb  + (size_t)4096 * 2048;        // [4096][2048]
  unsigned short* qkvwb  = xb     + (size_t)4096 * 2048;        // [6144][2048]
  unsigned short* projwb = qkvwb  + (size_t)6144 * 2048;        // [2048][2048]
  unsigned short* vT     = xb;                                  // overlay (xb dead after gemm1)
  float* out = (float*)d_out;                                   // [4096][2048] f32

  static bool attr_set = false;
  if (!attr_set) {
    hipFuncSetAttribute((const void*)gemm256_bt<true>,
                        hipFuncAttributeMaxDynamicSharedMemorySize, 131072);
    attr_set = true;
  }

  cvt3_f32_bf16<<<4096 + 6144 + 2048, 256, 0, stream>>>(
      x, xb, 4096, qkvw, qkvwb, 6144, projw, projwb);
  gemm256_bt<true><<<dim3(6144 / 256, 4096 / 256), 512, 131072, stream>>>(
      xb, qkvwb, qkvb, 4096, 6144, 2048);
  vtrans<<<dim3(32, 32), 256, 0, stream>>>(qkvb, vT);
  attn_fwd<<<1024, 256, 0, stream>>>(qkvb, vT, attnb);
  gemm_bt16<false><<<dim3(2048 / 128, 4096 / 128), 256, 0, stream>>>(
      attnb, projwb, out, 4096, 2048, 2048);
}

// Round 15
// 255.049 us; speedup vs baseline: 1.3994x; 1.0361x over previous
//
#include <hip/hip_runtime.h>

typedef __bf16 bf16x8 __attribute__((ext_vector_type(8)));
typedef float f32x4 __attribute__((ext_vector_type(4)));
typedef unsigned short u16x8 __attribute__((ext_vector_type(8)));

__device__ __forceinline__ unsigned short f2bf(float f) {
  return __builtin_bit_cast(unsigned short, (__bf16)f);   // v_cvt_pk_bf16_f32, RNE
}

__device__ __forceinline__ void gload16(const void* g, void* l) {
  __builtin_amdgcn_global_load_lds((const __attribute__((address_space(1))) unsigned int*)g,
                                   (__attribute__((address_space(3))) unsigned int*)l,
                                   16, 0, 0);
}

// DPP row_ror reductions over 16-lane rows (VALU pipe, no LDS traffic)
template <int N>
__device__ __forceinline__ float rormax(float x) {
  int r = __builtin_amdgcn_update_dpp(0, __builtin_bit_cast(int, x), 0x120 + N, 0xF, 0xF, true);
  return fmaxf(x, __builtin_bit_cast(float, r));
}
template <int N>
__device__ __forceinline__ float rorsum(float x) {
  int r = __builtin_amdgcn_update_dpp(0, __builtin_bit_cast(int, x), 0x120 + N, 0xF, 0xF, true);
  return x + __builtin_bit_cast(float, r);
}
__device__ __forceinline__ float red16max(float x) {
  x = rormax<8>(x); x = rormax<4>(x); x = rormax<2>(x); return rormax<1>(x);
}
__device__ __forceinline__ float red16sum(float x) {
  x = rorsum<8>(x); x = rorsum<4>(x); x = rorsum<2>(x); return rorsum<1>(x);
}

// ---------------------------------------------------------------------------
// f32 -> bf16 conversion for {x, qkv_w, proj_w}
// ---------------------------------------------------------------------------
__global__ __launch_bounds__(256)
void cvt3_f32_bf16(const float* __restrict__ s0, unsigned short* __restrict__ d0, int n0,
                   const float* __restrict__ s1, unsigned short* __restrict__ d1, int n1,
                   const float* __restrict__ s2, unsigned short* __restrict__ d2)
{
  int blk = blockIdx.x;
  const float* s; unsigned short* d;
  if (blk < n0)            { s = s0; d = d0; }
  else if (blk < n0 + n1)  { s = s1; d = d1; blk -= n0; }
  else                     { s = s2; d = d2; blk -= n0 + n1; }
  const size_t e = ((size_t)blk * 256 + threadIdx.x) * 8;
  const float4 a = *(const float4*)(s + e);
  const float4 b = *(const float4*)(s + e + 4);
  u16x8 v;
  v[0] = f2bf(a.x); v[1] = f2bf(a.y); v[2] = f2bf(a.z); v[3] = f2bf(a.w);
  v[4] = f2bf(b.x); v[5] = f2bf(b.y); v[6] = f2bf(b.z); v[7] = f2bf(b.w);
  *(u16x8*)(d + e) = v;
}

// ---------------------------------------------------------------------------
// 256x256 8-phase GEMM (R8 config — best wall evidence). Unchanged.
// ---------------------------------------------------------------------------
#define STG(XS, Xg, buf, half, kt)                                              \
  { gload16((Xg) + (size_t)((half)*128 + srow8) * K + (kt)*64 + scol,           \
            (XS) + (buf)*32768 + (half)*16384 + wid*1024);                      \
    gload16((Xg) + (size_t)((half)*128 + 64 + srow8) * K + (kt)*64 + scol,      \
            (XS) + (buf)*32768 + (half)*16384 + 8192 + wid*1024); }

#define LDA(buf, ih)                                                            \
  { _Pragma("unroll") for (int i = 0; i < 4; ++i) {                             \
      const int ro = (buf)*32768 + arow + ((ih)*64 + i*16)*128;                 \
      af[i][0] = *(const bf16x8*)(As + ro + cbs0);                              \
      af[i][1] = *(const bf16x8*)(As + ro + cbs1); } }

#define LDB(buf, jh, BF)                                                        \
  { _Pragma("unroll") for (int j = 0; j < 2; ++j) {                             \
      const int ro = (buf)*32768 + brow + (((jh)*2 + j)*16)*128;                \
      BF[j][0] = *(const bf16x8*)(Bs + ro + cbs0);                              \
      BF[j][1] = *(const bf16x8*)(Bs + ro + cbs1); } }

#define MM(ih, jh, BF)                                                          \
  { _Pragma("unroll") for (int i = 0; i < 4; ++i)                               \
    _Pragma("unroll") for (int j = 0; j < 2; ++j)                               \
    _Pragma("unroll") for (int kk = 0; kk < 2; ++kk)                            \
      acc[(ih)*4+i][(jh)*2+j] = __builtin_amdgcn_mfma_f32_16x16x32_bf16(        \
          af[i][kk], BF[j][kk], acc[(ih)*4+i][(jh)*2+j], 0, 0, 0); }

#define BAR1_12() { asm volatile("s_waitcnt lgkmcnt(8)" ::: "memory");          \
                    __builtin_amdgcn_s_barrier();                               \
                    asm volatile("s_waitcnt lgkmcnt(0)" ::: "memory");          \
                    __builtin_amdgcn_sched_barrier(0);                          \
                    __builtin_amdgcn_s_setprio(1); }
#define BAR1()    { __builtin_amdgcn_s_barrier();                               \
                    asm volatile("s_waitcnt lgkmcnt(0)" ::: "memory");          \
                    __builtin_amdgcn_sched_barrier(0);                          \
                    __builtin_amdgcn_s_setprio(1); }
#define BAR2()    { __builtin_amdgcn_s_setprio(0); __builtin_amdgcn_s_barrier(); }
#define BAR2V()   { __builtin_amdgcn_s_setprio(0);                              \
                    asm volatile("s_waitcnt vmcnt(4)" ::: "memory");            \
                    __builtin_amdgcn_s_barrier(); }

template <bool OUTBF16>
__global__ __launch_bounds__(512, 1)
void gemm256_bt(const unsigned short* __restrict__ Ap, const unsigned short* __restrict__ Bp,
                void* __restrict__ Outp, int M, int N, int K)
{
  extern __shared__ __align__(16) char smem[];
  char* const As = smem;            // [2][256 rows][64 k] bf16, 64KB
  char* const Bs = smem + 65536;
  const int tid = threadIdx.x;
  const int wid = tid >> 6, lane = tid & 63;
  const int wm = wid >> 2, wn = wid & 3;
  const int lg = lane >> 4, lr = lane & 15;

  const int gx = gridDim.x;
  const int nwg = gx * (int)gridDim.y;
  int bid = (int)blockIdx.y * gx + (int)blockIdx.x;
  bid = (bid & 7) * (nwg >> 3) + (bid >> 3);   // bijective: nwg % 8 == 0
  const int m0 = (bid / gx) * 256, n0 = (bid % gx) * 256;

  const int srow8 = wid * 8 + (lane >> 3);
  const int scol  = (((lane & 7) ^ (lane >> 3)) << 3);
  const unsigned short* const Ag = Ap + (size_t)m0 * K;
  const unsigned short* const Bg = Bp + (size_t)n0 * K;

  const int cbs0 = (lg * 16) ^ ((lr & 7) << 4);
  const int cbs1 = (64 + lg * 16) ^ ((lr & 7) << 4);
  const int arow = (wm * 128 + lr) * 128;
  const int brow = (wn * 64 + lr) * 128;

  const f32x4 z4 = {0.f, 0.f, 0.f, 0.f};
  f32x4 acc[8][4];
#pragma unroll
  for (int i = 0; i < 8; ++i)
#pragma unroll
    for (int j = 0; j < 4; ++j) acc[i][j] = z4;

  const int NKT = K >> 6;
  bf16x8 af[4][2], bf01[2][2], bf23[2][2];

  STG(As, Ag, 0, 0, 0); STG(As, Ag, 0, 1, 0);
  STG(Bs, Bg, 0, 0, 0); STG(Bs, Bg, 0, 1, 0);
  STG(Bs, Bg, 1, 0, 1); STG(Bs, Bg, 1, 1, 1);
  asm volatile("s_waitcnt vmcnt(4)" ::: "memory");
  __builtin_amdgcn_s_barrier();

  for (int it = 0; it < (NKT >> 1); ++it) {
    const int t1  = 2 * it + 1;
    const int t0n = (2 * it + 2 < NKT) ? 2 * it + 2 : NKT - 1;
    const int t1n = (t1 + 2 < NKT) ? t1 + 2 : NKT - 1;

    LDA(0, 0); LDB(0, 0, bf01); STG(As, Ag, 1, 0, t1);
    BAR1_12(); MM(0, 0, bf01); BAR2();
    LDB(0, 1, bf23); STG(As, Ag, 1, 1, t1);
    BAR1(); MM(0, 1, bf23); BAR2();
    LDA(0, 1); STG(Bs, Bg, 0, 0, t0n);
    BAR1(); MM(1, 0, bf01); BAR2();
    STG(Bs, Bg, 0, 1, t0n);
    BAR1(); MM(1, 1, bf23); BAR2V();
    LDA(1, 0); LDB(1, 0, bf01); STG(As, Ag, 0, 0, t0n);
    BAR1_12(); MM(0, 0, bf01); BAR2();
    LDB(1, 1, bf23); STG(As, Ag, 0, 1, t0n);
    BAR1(); MM(0, 1, bf23); BAR2();
    LDA(1, 1); STG(Bs, Bg, 1, 0, t1n);
    BAR1(); MM(1, 0, bf01); BAR2();
    STG(Bs, Bg, 1, 1, t1n);
    BAR1(); MM(1, 1, bf23); BAR2V();
  }
  asm volatile("s_waitcnt vmcnt(0)" ::: "memory");

#pragma unroll
  for (int i = 0; i < 8; ++i)
#pragma unroll
    for (int j = 0; j < 4; ++j)
#pragma unroll
      for (int r = 0; r < 4; ++r) {
        const int row = m0 + wm * 128 + i * 16 + lg * 4 + r;
        const int col = n0 + wn * 64 + j * 16 + lr;
        const float val = acc[i][j][r];
        if (OUTBF16) ((unsigned short*)Outp)[(size_t)row * N + col] = f2bf(val);
        else         ((float*)Outp)[(size_t)row * N + col] = val;
      }
}

// ---------------------------------------------------------------------------
// GEMM (m97 structure) + XCD swizzle — gemm3 (N=2048: 512 blocks).
// ---------------------------------------------------------------------------
template <bool OUTBF16>
__global__ __launch_bounds__(256, 2)
void gemm_bt16(const unsigned short* __restrict__ Ap, const unsigned short* __restrict__ Bp,
               void* __restrict__ Outp, int M, int N, int K)
{
  __shared__ __align__(16) char smA[128 * 128];
  __shared__ __align__(16) char smB[128 * 128];
  const int tid = threadIdx.x;
  const int wid = tid >> 6, lane = tid & 63;
  const int wr = wid >> 1, wc = wid & 1;
  const int lg = lane >> 4, lr = lane & 15;

  const int gx = gridDim.x;
  const int nwg = gx * gridDim.y;
  int bid = blockIdx.y * gx + blockIdx.x;
  bid = (bid & 7) * (nwg >> 3) + (bid >> 3);
  const int m0 = (bid / gx) * 128, n0 = (bid % gx) * 128;

  const int srow = wid * 8 + (lane >> 3);
  const int scol = (((lane & 7) ^ (lane >> 3)) << 3);
  const int lbase = wid * 1024;

  const f32x4 z4 = {0.f, 0.f, 0.f, 0.f};
  f32x4 acc[4][4];
#pragma unroll
  for (int i = 0; i < 4; ++i)
#pragma unroll
    for (int j = 0; j < 4; ++j) acc[i][j] = z4;

  for (int k0 = 0; k0 < K; k0 += 64) {
    __syncthreads();
#pragma unroll
    for (int c = 0; c < 4; ++c) {
      const int row = c * 32 + srow;
      gload16(Ap + (size_t)(m0 + row) * K + k0 + scol, smA + c * 4096 + lbase);
      gload16(Bp + (size_t)(n0 + row) * K + k0 + scol, smB + c * 4096 + lbase);
    }
    __syncthreads();
#pragma unroll
    for (int kk = 0; kk < 2; ++kk) {
      const int cb = (kk * 32 + lg * 8) * 2;
      bf16x8 a4[4], b4[4];
#pragma unroll
      for (int i = 0; i < 4; ++i) {
        const int row = wr * 64 + i * 16 + lr;
        a4[i] = *(const bf16x8*)(smA + row * 128 + (cb ^ ((row & 7) << 4)));
      }
#pragma unroll
      for (int j = 0; j < 4; ++j) {
        const int row = wc * 64 + j * 16 + lr;
        b4[j] = *(const bf16x8*)(smB + row * 128 + (cb ^ ((row & 7) << 4)));
      }
#pragma unroll
      for (int i = 0; i < 4; ++i)
#pragma unroll
        for (int j = 0; j < 4; ++j)
          acc[i][j] = __builtin_amdgcn_mfma_f32_16x16x32_bf16(a4[i], b4[j], acc[i][j], 0, 0, 0);
    }
  }
#pragma unroll
  for (int i = 0; i < 4; ++i)
#pragma unroll
    for (int j = 0; j < 4; ++j)
#pragma unroll
      for (int r = 0; r < 4; ++r) {
        const int row = m0 + wr * 64 + i * 16 + lg * 4 + r;
        const int col = n0 + wc * 64 + j * 16 + lr;
        const float val = acc[i][j][r];
        if (OUTBF16) ((unsigned short*)Outp)[(size_t)row * N + col] = f2bf(val);
        else         ((float*)Outp)[(size_t)row * N + col] = val;
      }
}

// ---------------------------------------------------------------------------
// V transpose: qkv V-part -> vT[(bh*128+d)*2048 + t]   (unchanged)
// ---------------------------------------------------------------------------
__global__ __launch_bounds__(256)
void vtrans(const unsigned short* __restrict__ qkv, unsigned short* __restrict__ vT)
{
  constexpr int T = 2048, ROWS = 6144;
  const int bh = blockIdx.y, b = bh >> 4, h = bh & 15;
  const int t0 = blockIdx.x * 64;
  const int tid = threadIdx.x;
  __shared__ __align__(16) char Sc[64 * 256];

#pragma unroll
  for (int c = 0; c < 4; ++c) {
    const int row = c * 16 + (tid >> 4);
    const int col = (tid & 15) * 8;
    u16x8 v = *(const u16x8*)(qkv + (size_t)(b * T + t0 + row) * ROWS + 4096 + h * 128 + col);
    *(u16x8*)(Sc + row * 256 + ((col * 2) ^ ((row & 7) << 4))) = v;
  }
  __syncthreads();
#pragma unroll
  for (int c = 0; c < 4; ++c) {
    const int d = c * 32 + (tid >> 3);
    const int t = (tid & 7) * 8;
    u16x8 v;
#pragma unroll
    for (int i = 0; i < 8; ++i)
      v[i] = *(const unsigned short*)(Sc + (t + i) * 256 + ((d * 2) ^ (((t + i) & 7) << 4)));
    *(u16x8*)(vT + ((size_t)bh * 128 + d) * 2048 + t0 + t) = v;
  }
}

// ---------------------------------------------------------------------------
// Flash attention v8 (R8 best-wall config) + T5 setprio around MFMA clusters
// (2 independent blocks/CU at staggered phases -> role diversity, m191 case).
// KVBLK=128, qt descending, log2 softmax, T13 defer-max. LDS 80KB, 2 blk/CU.
// ---------------------------------------------------------------------------
__global__ __launch_bounds__(256, 2)
void attn_fwd(const unsigned short* __restrict__ qkv, const unsigned short* __restrict__ vT,
              unsigned short* __restrict__ outp)
{
  constexpr int T = 2048, ROWS = 6144;
  const int blk = blockIdx.x;
  const int qt = 31 - (blk >> 5);       // heavy tiles first
  const int bh = blk & 31;
  const int b = bh >> 4, h = bh & 15;
  const int q0 = qt * 64;
  const int tid = threadIdx.x;
  const int wid = tid >> 6, lane = tid & 63;
  const int lg = lane >> 4, lr = lane & 15;

  __shared__ __align__(16) char Ks[128 * 256];  // 32KB [128 k][128 d] swizzled
  __shared__ __align__(16) char Vt[128 * 256];  // 32KB [128 d][128 k] swizzled
  __shared__ __align__(16) char Ps[64 * 256];   // 16KB [64 q][128 k] swizzled

  const int srow = wid * 4 + (lane >> 4);
  const int scol = (((lane & 15) ^ (srow & 7)) << 3);

  const size_t qrow = (size_t)(b * T + q0 + wid * 16 + lr) * ROWS + h * 128;
  bf16x8 qf[4];
#pragma unroll
  for (int kd = 0; kd < 4; ++kd)
    qf[kd] = __builtin_bit_cast(bf16x8, *(const u16x8*)(qkv + qrow + kd * 32 + lg * 8));

  const f32x4 z4 = {0.f, 0.f, 0.f, 0.f};
  f32x4 oacc[8];
#pragma unroll
  for (int jj = 0; jj < 8; ++jj) oacc[jj] = z4;
  float mrow[4] = {-1e30f, -1e30f, -1e30f, -1e30f};
  float lsum[4] = {0.f, 0.f, 0.f, 0.f};
  const float scale2 = 0.12751745f;   // (1/sqrt(128)) * log2(e)

  const int nt = (qt >> 1) + 1;
  for (int kt = 0; kt < nt; ++kt) {
    __syncthreads();
#pragma unroll
    for (int c = 0; c < 8; ++c) {
      gload16(qkv + (size_t)(b * T + kt * 128 + c * 16 + srow) * ROWS + 2048 + h * 128 + scol,
              Ks + c * 4096 + wid * 1024);
      gload16(vT + ((size_t)bh * 128 + c * 16 + srow) * 2048 + kt * 128 + scol,
              Vt + c * 4096 + wid * 1024);
    }
    asm volatile("s_waitcnt vmcnt(0)" ::: "memory");
    __syncthreads();

    // S = Q K^T  (T5: favor this wave while the CU's other block stages)
    f32x4 sf[8];
#pragma unroll
    for (int j = 0; j < 8; ++j) sf[j] = z4;
    __builtin_amdgcn_s_setprio(1);
#pragma unroll
    for (int kd = 0; kd < 4; ++kd) {
      const int cb = (kd * 32 + lg * 8) * 2;
#pragma unroll
      for (int j = 0; j < 8; ++j) {
        const int row = j * 16 + lr;
        bf16x8 kf = *(const bf16x8*)(Ks + row * 256 + (cb ^ ((row & 7) << 4)));
        sf[j] = __builtin_amdgcn_mfma_f32_16x16x32_bf16(qf[kd], kf, sf[j], 0, 0, 0);
      }
    }
    __builtin_amdgcn_s_setprio(0);

    const bool diag = (kt == nt - 1);
#pragma unroll
    for (int j = 0; j < 8; ++j)
#pragma unroll
      for (int r = 0; r < 4; ++r) {
        float s = sf[j][r] * scale2;
        const int key = kt * 128 + j * 16 + lr;
        const int qi  = q0 + wid * 16 + lg * 4 + r;
        if (diag && key > qi) s = -1e30f;
        sf[j][r] = s;
      }
    float pm[4];
#pragma unroll
    for (int r = 0; r < 4; ++r) {
      float m0 = fmaxf(fmaxf(sf[0][r], sf[1][r]), fmaxf(sf[2][r], sf[3][r]));
      float m1 = fmaxf(fmaxf(sf[4][r], sf[5][r]), fmaxf(sf[6][r], sf[7][r]));
      pm[r] = red16max(fmaxf(m0, m1));
    }
    const float growth = fmaxf(fmaxf(pm[0] - mrow[0], pm[1] - mrow[1]),
                               fmaxf(pm[2] - mrow[2], pm[3] - mrow[3]));
    const bool resc = !__all(growth <= 11.5f);
    float alpha[4];
    if (resc) {
#pragma unroll
      for (int r = 0; r < 4; ++r) {
        const float mn = fmaxf(mrow[r], pm[r]);
        alpha[r] = exp2f(mrow[r] - mn);
        mrow[r] = mn;
      }
    }
    float rs[4] = {0.f, 0.f, 0.f, 0.f};
#pragma unroll
    for (int j = 0; j < 8; ++j)
#pragma unroll
      for (int r = 0; r < 4; ++r) {
        const float p = exp2f(sf[j][r] - mrow[r]);
        sf[j][r] = p;
        rs[r] += p;
      }
    if (resc) {
#pragma unroll
      for (int r = 0; r < 4; ++r) lsum[r] = lsum[r] * alpha[r] + red16sum(rs[r]);
    } else {
#pragma unroll
      for (int r = 0; r < 4; ++r) lsum[r] += red16sum(rs[r]);
    }

#pragma unroll
    for (int j = 0; j < 8; ++j)
#pragma unroll
      for (int r = 0; r < 4; ++r) {
        const int prow = wid * 16 + lg * 4 + r;
        const int pcol = j * 16 + lr;
        *(unsigned short*)(Ps + prow * 256 + ((pcol * 2) ^ ((prow & 7) << 4))) = f2bf(sf[j][r]);
      }
    if (resc) {
#pragma unroll
      for (int jj = 0; jj < 8; ++jj)
#pragma unroll
        for (int r = 0; r < 4; ++r) oacc[jj][r] *= alpha[r];
    }
    asm volatile("s_waitcnt lgkmcnt(0)" ::: "memory");
    __builtin_amdgcn_sched_barrier(0);

    // O += P V  (T5 again)
    __builtin_amdgcn_s_setprio(1);
#pragma unroll
    for (int kk = 0; kk < 4; ++kk) {
      const int prow = wid * 16 + lr;
      const int pcb = (kk * 32 + lg * 8) * 2;
      bf16x8 pf = *(const bf16x8*)(Ps + prow * 256 + (pcb ^ ((prow & 7) << 4)));
#pragma unroll
      for (int jj = 0; jj < 8; ++jj) {
        const int vrow = jj * 16 + lr;
        bf16x8 vf = *(const bf16x8*)(Vt + vrow * 256 + (pcb ^ ((vrow & 7) << 4)));
        oacc[jj] = __builtin_amdgcn_mfma_f32_16x16x32_bf16(pf, vf, oacc[jj], 0, 0, 0);
      }
    }
    __builtin_amdgcn_s_setprio(0);
  }

  // epilogue
#pragma unroll
  for (int jj = 0; jj < 8; ++jj)
#pragma unroll
    for (int r = 0; r < 4; ++r) {
      const int q = q0 + wid * 16 + lg * 4 + r;
      const int col = h * 128 + jj * 16 + lr;
      const float o = oacc[jj][r] / lsum[r];
      outp[(size_t)(b * T + q) * 2048 + col] = f2bf(o);
    }
}

// ---------------------------------------------------------------------------
extern "C" void kernel_launch(void* const* d_in, const int* in_sizes, int n_in,
                              void* d_out, int out_size, void* d_ws, size_t ws_size,
                              hipStream_t stream) {
  (void)in_sizes; (void)n_in; (void)out_size; (void)ws_size;
  const float* x     = (const float*)d_in[0];   // [2,2048,2048]
  const float* qkvw  = (const float*)d_in[1];   // [6144,2048]
  const float* projw = (const float*)d_in[2];   // [2048,2048]

  unsigned short* qkvb   = (unsigned short*)d_ws;               // [4096][6144]
  unsigned short* attnb  = qkvb   + (size_t)4096 * 6144;        // [4096][2048]
  unsigned short* xb     = attnb  + (size_t)4096 * 2048;        // [4096][2048]
  unsigned short* qkvwb  = xb     + (size_t)4096 * 2048;        // [6144][2048]
  unsigned short* projwb = qkvwb  + (size_t)6144 * 2048;        // [2048][2048]
  unsigned short* vT     = xb;                                  // overlay (xb dead after gemm1)
  float* out = (float*)d_out;                                   // [4096][2048] f32

  static bool attr_set = false;
  if (!attr_set) {
    hipFuncSetAttribute((const void*)gemm256_bt<true>,
                        hipFuncAttributeMaxDynamicSharedMemorySize, 131072);
    attr_set = true;
  }

  cvt3_f32_bf16<<<4096 + 6144 + 2048, 256, 0, stream>>>(
      x, xb, 4096, qkvw, qkvwb, 6144, projw, projwb);
  gemm256_bt<true><<<dim3(6144 / 256, 4096 / 256), 512, 131072, stream>>>(
      xb, qkvwb, qkvb, 4096, 6144, 2048);
  vtrans<<<dim3(32, 32), 256, 0, stream>>>(qkvb, vT);
  attn_fwd<<<1024, 256, 0, stream>>>(qkvb, vT, attnb);
  gemm_bt16<false><<<dim3(2048 / 128, 4096 / 128), 256, 0, stream>>>(
      attnb, projwb, out, 4096, 2048, 2048);
}

// Round 16
// 253.137 us; speedup vs baseline: 1.4100x; 1.0076x over previous
//
#include <hip/hip_runtime.h>

typedef __bf16 bf16x8 __attribute__((ext_vector_type(8)));
typedef float f32x4 __attribute__((ext_vector_type(4)));
typedef unsigned short u16x8 __attribute__((ext_vector_type(8)));

__device__ __forceinline__ unsigned short f2bf(float f) {
  return __builtin_bit_cast(unsigned short, (__bf16)f);   // v_cvt_pk_bf16_f32, RNE
}

__device__ __forceinline__ void gload16(const void* g, void* l) {
  __builtin_amdgcn_global_load_lds((const __attribute__((address_space(1))) unsigned int*)g,
                                   (__attribute__((address_space(3))) unsigned int*)l,
                                   16, 0, 0);
}

// DPP row_ror reductions over 16-lane rows (VALU pipe, no LDS traffic)
template <int N>
__device__ __forceinline__ float rormax(float x) {
  int r = __builtin_amdgcn_update_dpp(0, __builtin_bit_cast(int, x), 0x120 + N, 0xF, 0xF, true);
  return fmaxf(x, __builtin_bit_cast(float, r));
}
template <int N>
__device__ __forceinline__ float rorsum(float x) {
  int r = __builtin_amdgcn_update_dpp(0, __builtin_bit_cast(int, x), 0x120 + N, 0xF, 0xF, true);
  return x + __builtin_bit_cast(float, r);
}
__device__ __forceinline__ float red16max(float x) {
  x = rormax<8>(x); x = rormax<4>(x); x = rormax<2>(x); return rormax<1>(x);
}
__device__ __forceinline__ float red16sum(float x) {
  x = rorsum<8>(x); x = rorsum<4>(x); x = rorsum<2>(x); return rorsum<1>(x);
}

// ---------------------------------------------------------------------------
// f32 -> bf16 conversion for {x, qkv_w, proj_w}
// ---------------------------------------------------------------------------
__global__ __launch_bounds__(256)
void cvt3_f32_bf16(const float* __restrict__ s0, unsigned short* __restrict__ d0, int n0,
                   const float* __restrict__ s1, unsigned short* __restrict__ d1, int n1,
                   const float* __restrict__ s2, unsigned short* __restrict__ d2)
{
  int blk = blockIdx.x;
  const float* s; unsigned short* d;
  if (blk < n0)            { s = s0; d = d0; }
  else if (blk < n0 + n1)  { s = s1; d = d1; blk -= n0; }
  else                     { s = s2; d = d2; blk -= n0 + n1; }
  const size_t e = ((size_t)blk * 256 + threadIdx.x) * 8;
  const float4 a = *(const float4*)(s + e);
  const float4 b = *(const float4*)(s + e + 4);
  u16x8 v;
  v[0] = f2bf(a.x); v[1] = f2bf(a.y); v[2] = f2bf(a.z); v[3] = f2bf(a.w);
  v[4] = f2bf(b.x); v[5] = f2bf(b.y); v[6] = f2bf(b.z); v[7] = f2bf(b.w);
  *(u16x8*)(d + e) = v;
}

// ---------------------------------------------------------------------------
// 256x192 8-phase GEMM for gemm1: grid 32x16 = 512 blocks = 2 EXACT rounds
// at 1 block/CU (fixes the 384-block 1.5-in-2-rounds quantization).
// 512 thr = 8 waves (2M x 4N); per-wave out 128x48 (8 i-frags x 3 j-frags).
// LDS 112KB: As[2][256][64] (64KB) + Bs[2][192][64] (48KB).
// B-tile = 3 x 64-row units. Ledger (drain-order verified): stage
// ph0-1:A(t1), ph2-3:B(t0n), ph4-5:A(t0n), ph6-7:B(t1n); vmcnt(3) at
// ph3/ph7/prologue (7 oldest = exactly the tile needed next).
// ---------------------------------------------------------------------------
#define SA(buf, half, kt)                                                       \
  { gload16(Ag + (size_t)((half)*128 + srow8) * K + (kt)*64 + scol,             \
            As + (buf)*32768 + (half)*16384 + wid*1024);                        \
    gload16(Ag + (size_t)((half)*128 + 64 + srow8) * K + (kt)*64 + scol,        \
            As + (buf)*32768 + (half)*16384 + 8192 + wid*1024); }

#define SB(buf, u, kt)                                                          \
  { gload16(Bg + (size_t)((u)*64 + srow8) * K + (kt)*64 + scol,                 \
            Bs + (buf)*24576 + (u)*8192 + wid*1024); }

#define LA(buf, ih)                                                             \
  { _Pragma("unroll") for (int i = 0; i < 4; ++i) {                             \
      const int ro = (buf)*32768 + arow + ((ih)*64 + i*16)*128;                 \
      af[i][0] = *(const bf16x8*)(As + ro + cbs0);                              \
      af[i][1] = *(const bf16x8*)(As + ro + cbs1); } }

#define LB2(buf)                                                                \
  { _Pragma("unroll") for (int j = 0; j < 2; ++j) {                             \
      const int ro = (buf)*24576 + brow + j*2048;                               \
      B2[j][0] = *(const bf16x8*)(Bs + ro + cbs0);                              \
      B2[j][1] = *(const bf16x8*)(Bs + ro + cbs1); } }

#define LB1(buf)                                                                \
  { const int ro = (buf)*24576 + brow + 4096;                                   \
    B1[0] = *(const bf16x8*)(Bs + ro + cbs0);                                   \
    B1[1] = *(const bf16x8*)(Bs + ro + cbs1); }

#define M2(ih)                                                                  \
  { _Pragma("unroll") for (int i = 0; i < 4; ++i)                               \
    _Pragma("unroll") for (int j = 0; j < 2; ++j)                               \
    _Pragma("unroll") for (int kk = 0; kk < 2; ++kk)                            \
      acc[(ih)*4+i][j] = __builtin_amdgcn_mfma_f32_16x16x32_bf16(               \
          af[i][kk], B2[j][kk], acc[(ih)*4+i][j], 0, 0, 0); }

#define M1(ih)                                                                  \
  { _Pragma("unroll") for (int i = 0; i < 4; ++i)                               \
    _Pragma("unroll") for (int kk = 0; kk < 2; ++kk)                            \
      acc[(ih)*4+i][2] = __builtin_amdgcn_mfma_f32_16x16x32_bf16(               \
          af[i][kk], B1[kk], acc[(ih)*4+i][2], 0, 0, 0); }

#define BAR1_12() { asm volatile("s_waitcnt lgkmcnt(8)" ::: "memory");          \
                    __builtin_amdgcn_s_barrier();                               \
                    asm volatile("s_waitcnt lgkmcnt(0)" ::: "memory");          \
                    __builtin_amdgcn_sched_barrier(0);                          \
                    __builtin_amdgcn_s_setprio(1); }
#define BAR1()    { __builtin_amdgcn_s_barrier();                               \
                    asm volatile("s_waitcnt lgkmcnt(0)" ::: "memory");          \
                    __builtin_amdgcn_sched_barrier(0);                          \
                    __builtin_amdgcn_s_setprio(1); }
#define BAR2()    { __builtin_amdgcn_s_setprio(0); __builtin_amdgcn_s_barrier(); }
#define BAR2V3()  { __builtin_amdgcn_s_setprio(0);                              \
                    asm volatile("s_waitcnt vmcnt(3)" ::: "memory");            \
                    __builtin_amdgcn_s_barrier(); }

__global__ __launch_bounds__(512, 1)
void gemm_n192(const unsigned short* __restrict__ Ap, const unsigned short* __restrict__ Bp,
               unsigned short* __restrict__ Outp, int M, int N, int K)
{
  extern __shared__ __align__(16) char smem[];
  char* const As = smem;            // [2][256 rows][64 k] bf16, 64KB
  char* const Bs = smem + 65536;    // [2][192 rows][64 k] bf16, 48KB
  const int tid = threadIdx.x;
  const int wid = tid >> 6, lane = tid & 63;
  const int wm = wid >> 2, wn = wid & 3;
  const int lg = lane >> 4, lr = lane & 15;

  const int gx = gridDim.x;                      // 32 N-tiles
  const int nwg = gx * (int)gridDim.y;
  int bid = (int)blockIdx.y * gx + (int)blockIdx.x;
  bid = (bid & 7) * (nwg >> 3) + (bid >> 3);     // bijective: nwg % 8 == 0
  const int m0 = (bid / gx) * 256, n0 = (bid % gx) * 192;

  const int srow8 = wid * 8 + (lane >> 3);
  const int scol  = (((lane & 7) ^ (lane >> 3)) << 3);
  const unsigned short* const Ag = Ap + (size_t)m0 * K;
  const unsigned short* const Bg = Bp + (size_t)n0 * K;

  const int cbs0 = (lg * 16) ^ ((lr & 7) << 4);
  const int cbs1 = (64 + lg * 16) ^ ((lr & 7) << 4);
  const int arow = (wm * 128 + lr) * 128;
  const int brow = (wn * 48 + lr) * 128;

  const f32x4 z4 = {0.f, 0.f, 0.f, 0.f};
  f32x4 acc[8][3];
#pragma unroll
  for (int i = 0; i < 8; ++i)
#pragma unroll
    for (int j = 0; j < 3; ++j) acc[i][j] = z4;

  const int NKT = K >> 6;
  bf16x8 af[4][2], B2[2][2], B1[2];

  // prologue: T0 A(4)+B(3), T1 B(3) = 10 gloads; drain 7 oldest = T0 resident
  SA(0, 0, 0); SA(0, 1, 0);
  SB(0, 0, 0); SB(0, 1, 0); SB(0, 2, 0);
  SB(1, 0, 1); SB(1, 1, 1); SB(1, 2, 1);
  asm volatile("s_waitcnt vmcnt(3)" ::: "memory");
  __builtin_amdgcn_s_barrier();

  for (int it = 0; it < (NKT >> 1); ++it) {
    const int t1  = 2 * it + 1;
    const int t0n = (2 * it + 2 < NKT) ? 2 * it + 2 : NKT - 1;
    const int t1n = (t1 + 2 < NKT) ? t1 + 2 : NKT - 1;

    // ph0: read T0 af(i0-3) + B2; stage A(t1)h0 -> buf1 (readers done prev ph6)
    LA(0, 0); LB2(0); SA(1, 0, t1);
    BAR1_12(); M2(0); BAR2();
    // ph1: read B1(T0); stage A(t1)h1
    LB1(0); SA(1, 1, t1);
    BAR1(); M1(0); BAR2();
    // ph2: read af(i4-7); stage B(t0n)u0,u1 -> buf0 (readers done ph1)
    LA(0, 1); SB(0, 0, t0n); SB(0, 1, t0n);
    BAR1(); M2(1); BAR2();
    // ph3: stage B(t0n)u2; drain 7 oldest = B(t1)+A(t1) -> buf1 resident
    SB(0, 2, t0n);
    BAR1(); M1(1); BAR2V3();
    // ph4: read T1 af(i0-3)+B2; stage A(t0n)h0 -> buf0 (readers done ph2)
    LA(1, 0); LB2(1); SA(0, 0, t0n);
    BAR1_12(); M2(0); BAR2();
    // ph5: read B1(T1); stage A(t0n)h1
    LB1(1); SA(0, 1, t0n);
    BAR1(); M1(0); BAR2();
    // ph6: read af(i4-7); stage B(t1n)u0,u1 -> buf1 (readers done ph5)
    LA(1, 1); SB(1, 0, t1n); SB(1, 1, t1n);
    BAR1(); M2(1); BAR2();
    // ph7: stage B(t1n)u2; drain 7 oldest = B(t0n)+A(t0n) -> buf0 resident
    SB(1, 2, t1n);
    BAR1(); M1(1); BAR2V3();
  }
  asm volatile("s_waitcnt vmcnt(0)" ::: "memory");

  // epilogue: C/D col=lane&15, row=(lane>>4)*4+reg; bf16 out
#pragma unroll
  for (int i = 0; i < 8; ++i)
#pragma unroll
    for (int j = 0; j < 3; ++j)
#pragma unroll
      for (int r = 0; r < 4; ++r) {
        const int row = m0 + wm * 128 + i * 16 + lg * 4 + r;
        const int col = n0 + wn * 48 + j * 16 + lr;
        Outp[(size_t)row * N + col] = f2bf(acc[i][j][r]);
      }
}

// ---------------------------------------------------------------------------
// GEMM (m97 structure) + XCD swizzle — gemm3 (N=2048: 512 blocks).
// ---------------------------------------------------------------------------
#define GSTG(XS, Xg, c)                                                         \
  gload16((Xg) + (size_t)(m_or_n + (c)*32 + srow) * K + k0 + scol,              \
          (XS) + (c)*4096 + lbase)

template <bool OUTBF16>
__global__ __launch_bounds__(256, 2)
void gemm_bt16(const unsigned short* __restrict__ Ap, const unsigned short* __restrict__ Bp,
               void* __restrict__ Outp, int M, int N, int K)
{
  __shared__ __align__(16) char smA[128 * 128];
  __shared__ __align__(16) char smB[128 * 128];
  const int tid = threadIdx.x;
  const int wid = tid >> 6, lane = tid & 63;
  const int wr = wid >> 1, wc = wid & 1;
  const int lg = lane >> 4, lr = lane & 15;

  const int gx = gridDim.x;
  const int nwg = gx * gridDim.y;
  int bid = blockIdx.y * gx + blockIdx.x;
  bid = (bid & 7) * (nwg >> 3) + (bid >> 3);
  const int m0 = (bid / gx) * 128, n0 = (bid % gx) * 128;

  const int srow = wid * 8 + (lane >> 3);
  const int scol = (((lane & 7) ^ (lane >> 3)) << 3);
  const int lbase = wid * 1024;

  const f32x4 z4 = {0.f, 0.f, 0.f, 0.f};
  f32x4 acc[4][4];
#pragma unroll
  for (int i = 0; i < 4; ++i)
#pragma unroll
    for (int j = 0; j < 4; ++j) acc[i][j] = z4;

  for (int k0 = 0; k0 < K; k0 += 64) {
    __syncthreads();
#pragma unroll
    for (int c = 0; c < 4; ++c) {
      const int row = c * 32 + srow;
      gload16(Ap + (size_t)(m0 + row) * K + k0 + scol, smA + c * 4096 + lbase);
      gload16(Bp + (size_t)(n0 + row) * K + k0 + scol, smB + c * 4096 + lbase);
    }
    __syncthreads();
#pragma unroll
    for (int kk = 0; kk < 2; ++kk) {
      const int cb = (kk * 32 + lg * 8) * 2;
      bf16x8 a4[4], b4[4];
#pragma unroll
      for (int i = 0; i < 4; ++i) {
        const int row = wr * 64 + i * 16 + lr;
        a4[i] = *(const bf16x8*)(smA + row * 128 + (cb ^ ((row & 7) << 4)));
      }
#pragma unroll
      for (int j = 0; j < 4; ++j) {
        const int row = wc * 64 + j * 16 + lr;
        b4[j] = *(const bf16x8*)(smB + row * 128 + (cb ^ ((row & 7) << 4)));
      }
#pragma unroll
      for (int i = 0; i < 4; ++i)
#pragma unroll
        for (int j = 0; j < 4; ++j)
          acc[i][j] = __builtin_amdgcn_mfma_f32_16x16x32_bf16(a4[i], b4[j], acc[i][j], 0, 0, 0);
    }
  }
#pragma unroll
  for (int i = 0; i < 4; ++i)
#pragma unroll
    for (int j = 0; j < 4; ++j)
#pragma unroll
      for (int r = 0; r < 4; ++r) {
        const int row = m0 + wr * 64 + i * 16 + lg * 4 + r;
        const int col = n0 + wc * 64 + j * 16 + lr;
        const float val = acc[i][j][r];
        if (OUTBF16) ((unsigned short*)Outp)[(size_t)row * N + col] = f2bf(val);
        else         ((float*)Outp)[(size_t)row * N + col] = val;
      }
}

// ---------------------------------------------------------------------------
// V transpose: qkv V-part -> vT[(bh*128+d)*2048 + t]   (unchanged)
// ---------------------------------------------------------------------------
__global__ __launch_bounds__(256)
void vtrans(const unsigned short* __restrict__ qkv, unsigned short* __restrict__ vT)
{
  constexpr int T = 2048, ROWS = 6144;
  const int bh = blockIdx.y, b = bh >> 4, h = bh & 15;
  const int t0 = blockIdx.x * 64;
  const int tid = threadIdx.x;
  __shared__ __align__(16) char Sc[64 * 256];

#pragma unroll
  for (int c = 0; c < 4; ++c) {
    const int row = c * 16 + (tid >> 4);
    const int col = (tid & 15) * 8;
    u16x8 v = *(const u16x8*)(qkv + (size_t)(b * T + t0 + row) * ROWS + 4096 + h * 128 + col);
    *(u16x8*)(Sc + row * 256 + ((col * 2) ^ ((row & 7) << 4))) = v;
  }
  __syncthreads();
#pragma unroll
  for (int c = 0; c < 4; ++c) {
    const int d = c * 32 + (tid >> 3);
    const int t = (tid & 7) * 8;
    u16x8 v;
#pragma unroll
    for (int i = 0; i < 8; ++i)
      v[i] = *(const unsigned short*)(Sc + (t + i) * 256 + ((d * 2) ^ (((t + i) & 7) << 4)));
    *(u16x8*)(vT + ((size_t)bh * 128 + d) * 2048 + t0 + t) = v;
  }
}

// ---------------------------------------------------------------------------
// Flash attention v8 + T5 setprio (R14 best-wall config, unchanged).
// ---------------------------------------------------------------------------
__global__ __launch_bounds__(256, 2)
void attn_fwd(const unsigned short* __restrict__ qkv, const unsigned short* __restrict__ vT,
              unsigned short* __restrict__ outp)
{
  constexpr int T = 2048, ROWS = 6144;
  const int blk = blockIdx.x;
  const int qt = 31 - (blk >> 5);       // heavy tiles first
  const int bh = blk & 31;
  const int b = bh >> 4, h = bh & 15;
  const int q0 = qt * 64;
  const int tid = threadIdx.x;
  const int wid = tid >> 6, lane = tid & 63;
  const int lg = lane >> 4, lr = lane & 15;

  __shared__ __align__(16) char Ks[128 * 256];  // 32KB [128 k][128 d] swizzled
  __shared__ __align__(16) char Vt[128 * 256];  // 32KB [128 d][128 k] swizzled
  __shared__ __align__(16) char Ps[64 * 256];   // 16KB [64 q][128 k] swizzled

  const int srow = wid * 4 + (lane >> 4);
  const int scol = (((lane & 15) ^ (srow & 7)) << 3);

  const size_t qrow = (size_t)(b * T + q0 + wid * 16 + lr) * ROWS + h * 128;
  bf16x8 qf[4];
#pragma unroll
  for (int kd = 0; kd < 4; ++kd)
    qf[kd] = __builtin_bit_cast(bf16x8, *(const u16x8*)(qkv + qrow + kd * 32 + lg * 8));

  const f32x4 z4 = {0.f, 0.f, 0.f, 0.f};
  f32x4 oacc[8];
#pragma unroll
  for (int jj = 0; jj < 8; ++jj) oacc[jj] = z4;
  float mrow[4] = {-1e30f, -1e30f, -1e30f, -1e30f};
  float lsum[4] = {0.f, 0.f, 0.f, 0.f};
  const float scale2 = 0.12751745f;   // (1/sqrt(128)) * log2(e)

  const int nt = (qt >> 1) + 1;
  for (int kt = 0; kt < nt; ++kt) {
    __syncthreads();
#pragma unroll
    for (int c = 0; c < 8; ++c) {
      gload16(qkv + (size_t)(b * T + kt * 128 + c * 16 + srow) * ROWS + 2048 + h * 128 + scol,
              Ks + c * 4096 + wid * 1024);
      gload16(vT + ((size_t)bh * 128 + c * 16 + srow) * 2048 + kt * 128 + scol,
              Vt + c * 4096 + wid * 1024);
    }
    asm volatile("s_waitcnt vmcnt(0)" ::: "memory");
    __syncthreads();

    f32x4 sf[8];
#pragma unroll
    for (int j = 0; j < 8; ++j) sf[j] = z4;
    __builtin_amdgcn_s_setprio(1);
#pragma unroll
    for (int kd = 0; kd < 4; ++kd) {
      const int cb = (kd * 32 + lg * 8) * 2;
#pragma unroll
      for (int j = 0; j < 8; ++j) {
        const int row = j * 16 + lr;
        bf16x8 kf = *(const bf16x8*)(Ks + row * 256 + (cb ^ ((row & 7) << 4)));
        sf[j] = __builtin_amdgcn_mfma_f32_16x16x32_bf16(qf[kd], kf, sf[j], 0, 0, 0);
      }
    }
    __builtin_amdgcn_s_setprio(0);

    const bool diag = (kt == nt - 1);
#pragma unroll
    for (int j = 0; j < 8; ++j)
#pragma unroll
      for (int r = 0; r < 4; ++r) {
        float s = sf[j][r] * scale2;
        const int key = kt * 128 + j * 16 + lr;
        const int qi  = q0 + wid * 16 + lg * 4 + r;
        if (diag && key > qi) s = -1e30f;
        sf[j][r] = s;
      }
    float pm[4];
#pragma unroll
    for (int r = 0; r < 4; ++r) {
      float m0 = fmaxf(fmaxf(sf[0][r], sf[1][r]), fmaxf(sf[2][r], sf[3][r]));
      float m1 = fmaxf(fmaxf(sf[4][r], sf[5][r]), fmaxf(sf[6][r], sf[7][r]));
      pm[r] = red16max(fmaxf(m0, m1));
    }
    const float growth = fmaxf(fmaxf(pm[0] - mrow[0], pm[1] - mrow[1]),
                               fmaxf(pm[2] - mrow[2], pm[3] - mrow[3]));
    const bool resc = !__all(growth <= 11.5f);
    float alpha[4];
    if (resc) {
#pragma unroll
      for (int r = 0; r < 4; ++r) {
        const float mn = fmaxf(mrow[r], pm[r]);
        alpha[r] = exp2f(mrow[r] - mn);
        mrow[r] = mn;
      }
    }
    float rs[4] = {0.f, 0.f, 0.f, 0.f};
#pragma unroll
    for (int j = 0; j < 8; ++j)
#pragma unroll
      for (int r = 0; r < 4; ++r) {
        const float p = exp2f(sf[j][r] - mrow[r]);
        sf[j][r] = p;
        rs[r] += p;
      }
    if (resc) {
#pragma unroll
      for (int r = 0; r < 4; ++r) lsum[r] = lsum[r] * alpha[r] + red16sum(rs[r]);
    } else {
#pragma unroll
      for (int r = 0; r < 4; ++r) lsum[r] += red16sum(rs[r]);
    }

#pragma unroll
    for (int j = 0; j < 8; ++j)
#pragma unroll
      for (int r = 0; r < 4; ++r) {
        const int prow = wid * 16 + lg * 4 + r;
        const int pcol = j * 16 + lr;
        *(unsigned short*)(Ps + prow * 256 + ((pcol * 2) ^ ((prow & 7) << 4))) = f2bf(sf[j][r]);
      }
    if (resc) {
#pragma unroll
      for (int jj = 0; jj < 8; ++jj)
#pragma unroll
        for (int r = 0; r < 4; ++r) oacc[jj][r] *= alpha[r];
    }
    asm volatile("s_waitcnt lgkmcnt(0)" ::: "memory");
    __builtin_amdgcn_sched_barrier(0);

    __builtin_amdgcn_s_setprio(1);
#pragma unroll
    for (int kk = 0; kk < 4; ++kk) {
      const int prow = wid * 16 + lr;
      const int pcb = (kk * 32 + lg * 8) * 2;
      bf16x8 pf = *(const bf16x8*)(Ps + prow * 256 + (pcb ^ ((prow & 7) << 4)));
#pragma unroll
      for (int jj = 0; jj < 8; ++jj) {
        const int vrow = jj * 16 + lr;
        bf16x8 vf = *(const bf16x8*)(Vt + vrow * 256 + (pcb ^ ((vrow & 7) << 4)));
        oacc[jj] = __builtin_amdgcn_mfma_f32_16x16x32_bf16(pf, vf, oacc[jj], 0, 0, 0);
      }
    }
    __builtin_amdgcn_s_setprio(0);
  }

  // epilogue
#pragma unroll
  for (int jj = 0; jj < 8; ++jj)
#pragma unroll
    for (int r = 0; r < 4; ++r) {
      const int q = q0 + wid * 16 + lg * 4 + r;
      const int col = h * 128 + jj * 16 + lr;
      const float o = oacc[jj][r] / lsum[r];
      outp[(size_t)(b * T + q) * 2048 + col] = f2bf(o);
    }
}

// ---------------------------------------------------------------------------
extern "C" void kernel_launch(void* const* d_in, const int* in_sizes, int n_in,
                              void* d_out, int out_size, void* d_ws, size_t ws_size,
                              hipStream_t stream) {
  (void)in_sizes; (void)n_in; (void)out_size; (void)ws_size;
  const float* x     = (const float*)d_in[0];   // [2,2048,2048]
  const float* qkvw  = (const float*)d_in[1];   // [6144,2048]
  const float* projw = (const float*)d_in[2];   // [2048,2048]

  unsigned short* qkvb   = (unsigned short*)d_ws;               // [4096][6144]
  unsigned short* attnb  = qkvb   + (size_t)4096 * 6144;        // [4096][2048]
  unsigned short* xb     = attnb  + (size_t)4096 * 2048;        // [4096][2048]
  unsigned short* qkvwb  = xb     + (size_t)4096 * 2048;        // [6144][2048]
  unsigned short* projwb = qkvwb  + (size_t)6144 * 2048;        // [2048][2048]
  unsigned short* vT     = xb;                                  // overlay (xb dead after gemm1)
  float* out = (float*)d_out;                                   // [4096][2048] f32

  static bool attr_set = false;
  if (!attr_set) {
    hipFuncSetAttribute((const void*)gemm_n192,
                        hipFuncAttributeMaxDynamicSharedMemorySize, 114688);
    attr_set = true;
  }

  cvt3_f32_bf16<<<4096 + 6144 + 2048, 256, 0, stream>>>(
      x, xb, 4096, qkvw, qkvwb, 6144, projw, projwb);
  // qkv projection: 4096 x 6144 x 2048; 256x192 tiles -> 512 blocks = 2 exact rounds
  gemm_n192<<<dim3(6144 / 192, 4096 / 256), 512, 114688, stream>>>(
      xb, qkvwb, qkvb, 4096, 6144, 2048);
  vtrans<<<dim3(32, 32), 256, 0, stream>>>(qkvb, vT);
  attn_fwd<<<1024, 256, 0, stream>>>(qkvb, vT, attnb);
  gemm_bt16<false><<<dim3(2048 / 128, 4096 / 128), 256, 0, stream>>>(
      attnb, projwb, out, 4096, 2048, 2048);
}

// Round 17
// 242.269 us; speedup vs baseline: 1.4732x; 1.0449x over previous
//
#include <hip/hip_runtime.h>

typedef __bf16 bf16x8 __attribute__((ext_vector_type(8)));
typedef float f32x4 __attribute__((ext_vector_type(4)));
typedef unsigned short u16x8 __attribute__((ext_vector_type(8)));
typedef unsigned short u16x4 __attribute__((ext_vector_type(4)));

__device__ __forceinline__ unsigned short f2bf(float f) {
  return __builtin_bit_cast(unsigned short, (__bf16)f);   // v_cvt_pk_bf16_f32, RNE
}

__device__ __forceinline__ void gload16(const void* g, void* l) {
  __builtin_amdgcn_global_load_lds((const __attribute__((address_space(1))) unsigned int*)g,
                                   (__attribute__((address_space(3))) unsigned int*)l,
                                   16, 0, 0);
}

// DPP row_ror reductions over 16-lane rows (VALU pipe, no LDS traffic)
template <int N>
__device__ __forceinline__ float rormax(float x) {
  int r = __builtin_amdgcn_update_dpp(0, __builtin_bit_cast(int, x), 0x120 + N, 0xF, 0xF, true);
  return fmaxf(x, __builtin_bit_cast(float, r));
}
template <int N>
__device__ __forceinline__ float rorsum(float x) {
  int r = __builtin_amdgcn_update_dpp(0, __builtin_bit_cast(int, x), 0x120 + N, 0xF, 0xF, true);
  return x + __builtin_bit_cast(float, r);
}
__device__ __forceinline__ float red16max(float x) {
  x = rormax<8>(x); x = rormax<4>(x); x = rormax<2>(x); return rormax<1>(x);
}
__device__ __forceinline__ float red16sum(float x) {
  x = rorsum<8>(x); x = rorsum<4>(x); x = rorsum<2>(x); return rorsum<1>(x);
}

// ---------------------------------------------------------------------------
// f32 -> bf16 conversion for {x, qkv_w, proj_w}
// ---------------------------------------------------------------------------
__global__ __launch_bounds__(256)
void cvt3_f32_bf16(const float* __restrict__ s0, unsigned short* __restrict__ d0, int n0,
                   const float* __restrict__ s1, unsigned short* __restrict__ d1, int n1,
                   const float* __restrict__ s2, unsigned short* __restrict__ d2)
{
  int blk = blockIdx.x;
  const float* s; unsigned short* d;
  if (blk < n0)            { s = s0; d = d0; }
  else if (blk < n0 + n1)  { s = s1; d = d1; blk -= n0; }
  else                     { s = s2; d = d2; blk -= n0 + n1; }
  const size_t e = ((size_t)blk * 256 + threadIdx.x) * 8;
  const float4 a = *(const float4*)(s + e);
  const float4 b = *(const float4*)(s + e + 4);
  u16x8 v;
  v[0] = f2bf(a.x); v[1] = f2bf(a.y); v[2] = f2bf(a.z); v[3] = f2bf(a.w);
  v[4] = f2bf(b.x); v[5] = f2bf(b.y); v[6] = f2bf(b.z); v[7] = f2bf(b.w);
  *(u16x8*)(d + e) = v;
}

// ---------------------------------------------------------------------------
// 256x192 8-phase GEMM for gemm1 (R15 ledger, proven) + fused V-transpose
// epilogue: cols <4096 (Q,K) -> QKout[row*4096+col] row-major; cols >=4096
// (V) -> vT[((b*16+h)*128+d)*2048 + t] directly (vtrans kernel deleted).
// V-frags are 16-col aligned -> wave-uniform branch; 4 r-rows pack into one
// 8B u16x4 store (t % 4 == 0).
// ---------------------------------------------------------------------------
#define SA(buf, half, kt)                                                       \
  { gload16(Ag + (size_t)((half)*128 + srow8) * K + (kt)*64 + scol,             \
            As + (buf)*32768 + (half)*16384 + wid*1024);                        \
    gload16(Ag + (size_t)((half)*128 + 64 + srow8) * K + (kt)*64 + scol,        \
            As + (buf)*32768 + (half)*16384 + 8192 + wid*1024); }

#define SB(buf, u, kt)                                                          \
  { gload16(Bg + (size_t)((u)*64 + srow8) * K + (kt)*64 + scol,                 \
            Bs + (buf)*24576 + (u)*8192 + wid*1024); }

#define LA(buf, ih)                                                             \
  { _Pragma("unroll") for (int i = 0; i < 4; ++i) {                             \
      const int ro = (buf)*32768 + arow + ((ih)*64 + i*16)*128;                 \
      af[i][0] = *(const bf16x8*)(As + ro + cbs0);                              \
      af[i][1] = *(const bf16x8*)(As + ro + cbs1); } }

#define LB2(buf)                                                                \
  { _Pragma("unroll") for (int j = 0; j < 2; ++j) {                             \
      const int ro = (buf)*24576 + brow + j*2048;                               \
      B2[j][0] = *(const bf16x8*)(Bs + ro + cbs0);                              \
      B2[j][1] = *(const bf16x8*)(Bs + ro + cbs1); } }

#define LB1(buf)                                                                \
  { const int ro = (buf)*24576 + brow + 4096;                                   \
    B1[0] = *(const bf16x8*)(Bs + ro + cbs0);                                   \
    B1[1] = *(const bf16x8*)(Bs + ro + cbs1); }

#define M2(ih)                                                                  \
  { _Pragma("unroll") for (int i = 0; i < 4; ++i)                               \
    _Pragma("unroll") for (int j = 0; j < 2; ++j)                               \
    _Pragma("unroll") for (int kk = 0; kk < 2; ++kk)                            \
      acc[(ih)*4+i][j] = __builtin_amdgcn_mfma_f32_16x16x32_bf16(               \
          af[i][kk], B2[j][kk], acc[(ih)*4+i][j], 0, 0, 0); }

#define M1(ih)                                                                  \
  { _Pragma("unroll") for (int i = 0; i < 4; ++i)                               \
    _Pragma("unroll") for (int kk = 0; kk < 2; ++kk)                            \
      acc[(ih)*4+i][2] = __builtin_amdgcn_mfma_f32_16x16x32_bf16(               \
          af[i][kk], B1[kk], acc[(ih)*4+i][2], 0, 0, 0); }

#define BAR1_12() { asm volatile("s_waitcnt lgkmcnt(8)" ::: "memory");          \
                    __builtin_amdgcn_s_barrier();                               \
                    asm volatile("s_waitcnt lgkmcnt(0)" ::: "memory");          \
                    __builtin_amdgcn_sched_barrier(0);                          \
                    __builtin_amdgcn_s_setprio(1); }
#define BAR1()    { __builtin_amdgcn_s_barrier();                               \
                    asm volatile("s_waitcnt lgkmcnt(0)" ::: "memory");          \
                    __builtin_amdgcn_sched_barrier(0);                          \
                    __builtin_amdgcn_s_setprio(1); }
#define BAR2()    { __builtin_amdgcn_s_setprio(0); __builtin_amdgcn_s_barrier(); }
#define BAR2V3()  { __builtin_amdgcn_s_setprio(0);                              \
                    asm volatile("s_waitcnt vmcnt(3)" ::: "memory");            \
                    __builtin_amdgcn_s_barrier(); }

__global__ __launch_bounds__(512, 1)
void gemm_n192(const unsigned short* __restrict__ Ap, const unsigned short* __restrict__ Bp,
               unsigned short* __restrict__ QKout, unsigned short* __restrict__ vT,
               int M, int N, int K)
{
  extern __shared__ __align__(16) char smem[];
  char* const As = smem;            // [2][256 rows][64 k] bf16, 64KB
  char* const Bs = smem + 65536;    // [2][192 rows][64 k] bf16, 48KB
  const int tid = threadIdx.x;
  const int wid = tid >> 6, lane = tid & 63;
  const int wm = wid >> 2, wn = wid & 3;
  const int lg = lane >> 4, lr = lane & 15;

  const int gx = gridDim.x;                      // 32 N-tiles
  const int nwg = gx * (int)gridDim.y;
  int bid = (int)blockIdx.y * gx + (int)blockIdx.x;
  bid = (bid & 7) * (nwg >> 3) + (bid >> 3);     // bijective: nwg % 8 == 0
  const int m0 = (bid / gx) * 256, n0 = (bid % gx) * 192;

  const int srow8 = wid * 8 + (lane >> 3);
  const int scol  = (((lane & 7) ^ (lane >> 3)) << 3);
  const unsigned short* const Ag = Ap + (size_t)m0 * K;
  const unsigned short* const Bg = Bp + (size_t)n0 * K;

  const int cbs0 = (lg * 16) ^ ((lr & 7) << 4);
  const int cbs1 = (64 + lg * 16) ^ ((lr & 7) << 4);
  const int arow = (wm * 128 + lr) * 128;
  const int brow = (wn * 48 + lr) * 128;

  const f32x4 z4 = {0.f, 0.f, 0.f, 0.f};
  f32x4 acc[8][3];
#pragma unroll
  for (int i = 0; i < 8; ++i)
#pragma unroll
    for (int j = 0; j < 3; ++j) acc[i][j] = z4;

  const int NKT = K >> 6;
  bf16x8 af[4][2], B2[2][2], B1[2];

  // prologue: T0 A(4)+B(3), T1 B(3) = 10 gloads; drain 7 oldest = T0 resident
  SA(0, 0, 0); SA(0, 1, 0);
  SB(0, 0, 0); SB(0, 1, 0); SB(0, 2, 0);
  SB(1, 0, 1); SB(1, 1, 1); SB(1, 2, 1);
  asm volatile("s_waitcnt vmcnt(3)" ::: "memory");
  __builtin_amdgcn_s_barrier();

  for (int it = 0; it < (NKT >> 1); ++it) {
    const int t1  = 2 * it + 1;
    const int t0n = (2 * it + 2 < NKT) ? 2 * it + 2 : NKT - 1;
    const int t1n = (t1 + 2 < NKT) ? t1 + 2 : NKT - 1;

    LA(0, 0); LB2(0); SA(1, 0, t1);
    BAR1_12(); M2(0); BAR2();
    LB1(0); SA(1, 1, t1);
    BAR1(); M1(0); BAR2();
    LA(0, 1); SB(0, 0, t0n); SB(0, 1, t0n);
    BAR1(); M2(1); BAR2();
    SB(0, 2, t0n);
    BAR1(); M1(1); BAR2V3();
    LA(1, 0); LB2(1); SA(0, 0, t0n);
    BAR1_12(); M2(0); BAR2();
    LB1(1); SA(0, 1, t0n);
    BAR1(); M1(0); BAR2();
    LA(1, 1); SB(1, 0, t1n); SB(1, 1, t1n);
    BAR1(); M2(1); BAR2();
    SB(1, 2, t1n);
    BAR1(); M1(1); BAR2V3();
  }
  asm volatile("s_waitcnt vmcnt(0)" ::: "memory");

  // epilogue: Q/K cols row-major into QKout[.][4096]; V cols transposed
  // into vT[((b*16+h)*128+d)*2048 + t] (16-col frags never straddle 4096)
#pragma unroll
  for (int i = 0; i < 8; ++i)
#pragma unroll
    for (int j = 0; j < 3; ++j) {
      const int colb = n0 + wn * 48 + j * 16;   // frag base (wave-uniform)
      const int row0 = m0 + wm * 128 + i * 16 + lg * 4;
      if (colb < 4096) {
#pragma unroll
        for (int r = 0; r < 4; ++r)
          QKout[(size_t)(row0 + r) * 4096 + colb + lr] = f2bf(acc[i][j][r]);
      } else {
        const int hcol = colb + lr - 4096;
        const int hh = hcol >> 7, d = hcol & 127;
        const int bb = row0 >> 11, t = row0 & 2047;
        u16x4 pack;
        pack[0] = f2bf(acc[i][j][0]); pack[1] = f2bf(acc[i][j][1]);
        pack[2] = f2bf(acc[i][j][2]); pack[3] = f2bf(acc[i][j][3]);
        *(u16x4*)(vT + ((size_t)(bb * 16 + hh) * 128 + d) * 2048 + t) = pack;
      }
    }
}

// ---------------------------------------------------------------------------
// GEMM (m97 structure) + XCD swizzle — gemm3 (N=2048: 512 blocks).
// ---------------------------------------------------------------------------
template <bool OUTBF16>
__global__ __launch_bounds__(256, 2)
void gemm_bt16(const unsigned short* __restrict__ Ap, const unsigned short* __restrict__ Bp,
               void* __restrict__ Outp, int M, int N, int K)
{
  __shared__ __align__(16) char smA[128 * 128];
  __shared__ __align__(16) char smB[128 * 128];
  const int tid = threadIdx.x;
  const int wid = tid >> 6, lane = tid & 63;
  const int wr = wid >> 1, wc = wid & 1;
  const int lg = lane >> 4, lr = lane & 15;

  const int gx = gridDim.x;
  const int nwg = gx * gridDim.y;
  int bid = blockIdx.y * gx + blockIdx.x;
  bid = (bid & 7) * (nwg >> 3) + (bid >> 3);
  const int m0 = (bid / gx) * 128, n0 = (bid % gx) * 128;

  const int srow = wid * 8 + (lane >> 3);
  const int scol = (((lane & 7) ^ (lane >> 3)) << 3);
  const int lbase = wid * 1024;

  const f32x4 z4 = {0.f, 0.f, 0.f, 0.f};
  f32x4 acc[4][4];
#pragma unroll
  for (int i = 0; i < 4; ++i)
#pragma unroll
    for (int j = 0; j < 4; ++j) acc[i][j] = z4;

  for (int k0 = 0; k0 < K; k0 += 64) {
    __syncthreads();
#pragma unroll
    for (int c = 0; c < 4; ++c) {
      const int row = c * 32 + srow;
      gload16(Ap + (size_t)(m0 + row) * K + k0 + scol, smA + c * 4096 + lbase);
      gload16(Bp + (size_t)(n0 + row) * K + k0 + scol, smB + c * 4096 + lbase);
    }
    __syncthreads();
#pragma unroll
    for (int kk = 0; kk < 2; ++kk) {
      const int cb = (kk * 32 + lg * 8) * 2;
      bf16x8 a4[4], b4[4];
#pragma unroll
      for (int i = 0; i < 4; ++i) {
        const int row = wr * 64 + i * 16 + lr;
        a4[i] = *(const bf16x8*)(smA + row * 128 + (cb ^ ((row & 7) << 4)));
      }
#pragma unroll
      for (int j = 0; j < 4; ++j) {
        const int row = wc * 64 + j * 16 + lr;
        b4[j] = *(const bf16x8*)(smB + row * 128 + (cb ^ ((row & 7) << 4)));
      }
#pragma unroll
      for (int i = 0; i < 4; ++i)
#pragma unroll
        for (int j = 0; j < 4; ++j)
          acc[i][j] = __builtin_amdgcn_mfma_f32_16x16x32_bf16(a4[i], b4[j], acc[i][j], 0, 0, 0);
    }
  }
#pragma unroll
  for (int i = 0; i < 4; ++i)
#pragma unroll
    for (int j = 0; j < 4; ++j)
#pragma unroll
      for (int r = 0; r < 4; ++r) {
        const int row = m0 + wr * 64 + i * 16 + lg * 4 + r;
        const int col = n0 + wc * 64 + j * 16 + lr;
        const float val = acc[i][j][r];
        if (OUTBF16) ((unsigned short*)Outp)[(size_t)row * N + col] = f2bf(val);
        else         ((float*)Outp)[(size_t)row * N + col] = val;
      }
}

// ---------------------------------------------------------------------------
// Flash attention v8 + T5 setprio (R14/R15 config); Q/K now read from the
// reshaped [4096][4096] QK buffer (stride 4096, K at col 2048); V from vT.
// ---------------------------------------------------------------------------
__global__ __launch_bounds__(256, 2)
void attn_fwd(const unsigned short* __restrict__ qk, const unsigned short* __restrict__ vT,
              unsigned short* __restrict__ outp)
{
  constexpr int T = 2048, ROWS = 4096;
  const int blk = blockIdx.x;
  const int qt = 31 - (blk >> 5);       // heavy tiles first
  const int bh = blk & 31;
  const int b = bh >> 4, h = bh & 15;
  const int q0 = qt * 64;
  const int tid = threadIdx.x;
  const int wid = tid >> 6, lane = tid & 63;
  const int lg = lane >> 4, lr = lane & 15;

  __shared__ __align__(16) char Ks[128 * 256];  // 32KB [128 k][128 d] swizzled
  __shared__ __align__(16) char Vt[128 * 256];  // 32KB [128 d][128 k] swizzled
  __shared__ __align__(16) char Ps[64 * 256];   // 16KB [64 q][128 k] swizzled

  const int srow = wid * 4 + (lane >> 4);
  const int scol = (((lane & 15) ^ (srow & 7)) << 3);

  const size_t qrow = (size_t)(b * T + q0 + wid * 16 + lr) * ROWS + h * 128;
  bf16x8 qf[4];
#pragma unroll
  for (int kd = 0; kd < 4; ++kd)
    qf[kd] = __builtin_bit_cast(bf16x8, *(const u16x8*)(qk + qrow + kd * 32 + lg * 8));

  const f32x4 z4 = {0.f, 0.f, 0.f, 0.f};
  f32x4 oacc[8];
#pragma unroll
  for (int jj = 0; jj < 8; ++jj) oacc[jj] = z4;
  float mrow[4] = {-1e30f, -1e30f, -1e30f, -1e30f};
  float lsum[4] = {0.f, 0.f, 0.f, 0.f};
  const float scale2 = 0.12751745f;   // (1/sqrt(128)) * log2(e)

  const int nt = (qt >> 1) + 1;
  for (int kt = 0; kt < nt; ++kt) {
    __syncthreads();
#pragma unroll
    for (int c = 0; c < 8; ++c) {
      gload16(qk + (size_t)(b * T + kt * 128 + c * 16 + srow) * ROWS + 2048 + h * 128 + scol,
              Ks + c * 4096 + wid * 1024);
      gload16(vT + ((size_t)bh * 128 + c * 16 + srow) * 2048 + kt * 128 + scol,
              Vt + c * 4096 + wid * 1024);
    }
    asm volatile("s_waitcnt vmcnt(0)" ::: "memory");
    __syncthreads();

    f32x4 sf[8];
#pragma unroll
    for (int j = 0; j < 8; ++j) sf[j] = z4;
    __builtin_amdgcn_s_setprio(1);
#pragma unroll
    for (int kd = 0; kd < 4; ++kd) {
      const int cb = (kd * 32 + lg * 8) * 2;
#pragma unroll
      for (int j = 0; j < 8; ++j) {
        const int row = j * 16 + lr;
        bf16x8 kf = *(const bf16x8*)(Ks + row * 256 + (cb ^ ((row & 7) << 4)));
        sf[j] = __builtin_amdgcn_mfma_f32_16x16x32_bf16(qf[kd], kf, sf[j], 0, 0, 0);
      }
    }
    __builtin_amdgcn_s_setprio(0);

    const bool diag = (kt == nt - 1);
#pragma unroll
    for (int j = 0; j < 8; ++j)
#pragma unroll
      for (int r = 0; r < 4; ++r) {
        float s = sf[j][r] * scale2;
        const int key = kt * 128 + j * 16 + lr;
        const int qi  = q0 + wid * 16 + lg * 4 + r;
        if (diag && key > qi) s = -1e30f;
        sf[j][r] = s;
      }
    float pm[4];
#pragma unroll
    for (int r = 0; r < 4; ++r) {
      float m0 = fmaxf(fmaxf(sf[0][r], sf[1][r]), fmaxf(sf[2][r], sf[3][r]));
      float m1 = fmaxf(fmaxf(sf[4][r], sf[5][r]), fmaxf(sf[6][r], sf[7][r]));
      pm[r] = red16max(fmaxf(m0, m1));
    }
    const float growth = fmaxf(fmaxf(pm[0] - mrow[0], pm[1] - mrow[1]),
                               fmaxf(pm[2] - mrow[2], pm[3] - mrow[3]));
    const bool resc = !__all(growth <= 11.5f);
    float alpha[4];
    if (resc) {
#pragma unroll
      for (int r = 0; r < 4; ++r) {
        const float mn = fmaxf(mrow[r], pm[r]);
        alpha[r] = exp2f(mrow[r] - mn);
        mrow[r] = mn;
      }
    }
    float rs[4] = {0.f, 0.f, 0.f, 0.f};
#pragma unroll
    for (int j = 0; j < 8; ++j)
#pragma unroll
      for (int r = 0; r < 4; ++r) {
        const float p = exp2f(sf[j][r] - mrow[r]);
        sf[j][r] = p;
        rs[r] += p;
      }
    if (resc) {
#pragma unroll
      for (int r = 0; r < 4; ++r) lsum[r] = lsum[r] * alpha[r] + red16sum(rs[r]);
    } else {
#pragma unroll
      for (int r = 0; r < 4; ++r) lsum[r] += red16sum(rs[r]);
    }

#pragma unroll
    for (int j = 0; j < 8; ++j)
#pragma unroll
      for (int r = 0; r < 4; ++r) {
        const int prow = wid * 16 + lg * 4 + r;
        const int pcol = j * 16 + lr;
        *(unsigned short*)(Ps + prow * 256 + ((pcol * 2) ^ ((prow & 7) << 4))) = f2bf(sf[j][r]);
      }
    if (resc) {
#pragma unroll
      for (int jj = 0; jj < 8; ++jj)
#pragma unroll
        for (int r = 0; r < 4; ++r) oacc[jj][r] *= alpha[r];
    }
    asm volatile("s_waitcnt lgkmcnt(0)" ::: "memory");
    __builtin_amdgcn_sched_barrier(0);

    __builtin_amdgcn_s_setprio(1);
#pragma unroll
    for (int kk = 0; kk < 4; ++kk) {
      const int prow = wid * 16 + lr;
      const int pcb = (kk * 32 + lg * 8) * 2;
      bf16x8 pf = *(const bf16x8*)(Ps + prow * 256 + (pcb ^ ((prow & 7) << 4)));
#pragma unroll
      for (int jj = 0; jj < 8; ++jj) {
        const int vrow = jj * 16 + lr;
        bf16x8 vf = *(const bf16x8*)(Vt + vrow * 256 + (pcb ^ ((vrow & 7) << 4)));
        oacc[jj] = __builtin_amdgcn_mfma_f32_16x16x32_bf16(pf, vf, oacc[jj], 0, 0, 0);
      }
    }
    __builtin_amdgcn_s_setprio(0);
  }

  // epilogue
#pragma unroll
  for (int jj = 0; jj < 8; ++jj)
#pragma unroll
    for (int r = 0; r < 4; ++r) {
      const int q = q0 + wid * 16 + lg * 4 + r;
      const int col = h * 128 + jj * 16 + lr;
      const float o = oacc[jj][r] / lsum[r];
      outp[(size_t)(b * T + q) * 2048 + col] = f2bf(o);
    }
}

// ---------------------------------------------------------------------------
extern "C" void kernel_launch(void* const* d_in, const int* in_sizes, int n_in,
                              void* d_out, int out_size, void* d_ws, size_t ws_size,
                              hipStream_t stream) {
  (void)in_sizes; (void)n_in; (void)out_size; (void)ws_size;
  const float* x     = (const float*)d_in[0];   // [2,2048,2048]
  const float* qkvw  = (const float*)d_in[1];   // [6144,2048]
  const float* projw = (const float*)d_in[2];   // [2048,2048]

  // qkvb region (25.2M elems) reshaped: QK row-major [4096][4096] + V^T
  unsigned short* qkb    = (unsigned short*)d_ws;               // [4096][4096]
  unsigned short* vT     = qkb + (size_t)4096 * 4096;           // [32*128][2048]
  unsigned short* attnb  = qkb + (size_t)4096 * 6144;           // [4096][2048]
  unsigned short* xb     = attnb  + (size_t)4096 * 2048;        // [4096][2048]
  unsigned short* qkvwb  = xb     + (size_t)4096 * 2048;        // [6144][2048]
  unsigned short* projwb = qkvwb  + (size_t)6144 * 2048;        // [2048][2048]
  float* out = (float*)d_out;                                   // [4096][2048] f32

  static bool attr_set = false;
  if (!attr_set) {
    hipFuncSetAttribute((const void*)gemm_n192,
                        hipFuncAttributeMaxDynamicSharedMemorySize, 114688);
    attr_set = true;
  }

  cvt3_f32_bf16<<<4096 + 6144 + 2048, 256, 0, stream>>>(
      x, xb, 4096, qkvw, qkvwb, 6144, projw, projwb);
  // qkv projection with fused V-transpose epilogue (vtrans deleted)
  gemm_n192<<<dim3(6144 / 192, 4096 / 256), 512, 114688, stream>>>(
      xb, qkvwb, qkb, vT, 4096, 6144, 2048);
  attn_fwd<<<1024, 256, 0, stream>>>(qkb, vT, attnb);
  gemm_bt16<false><<<dim3(2048 / 128, 4096 / 128), 256, 0, stream>>>(
      attnb, projwb, out, 4096, 2048, 2048);
}